// Round 3
// baseline (730.419 us; speedup 1.0000x reference)
//
#include <hip/hip_runtime.h>

typedef unsigned short u16;
typedef __attribute__((ext_vector_type(8))) short  s16x8;
typedef __attribute__((ext_vector_type(8))) u16    u16x8;
typedef __attribute__((ext_vector_type(4))) float  f32x4;

#define NB    8
#define HH    56
#define WWI   56
#define CDIM  512
#define CQKV  1536
#define P2C   49
#define NROWS (NB*P2C*64)      // 25088 windowed pixel rows
#define SCALE_F 0.04419417382415922f

__device__ __forceinline__ u16 f2bf(float f) {
  union { float f; unsigned u; } x; x.f = f;
  unsigned r = x.u + 0x7fffu + ((x.u >> 16) & 1u);
  return (u16)(r >> 16);
}
__device__ __forceinline__ float bf2f(u16 h) {
  union { unsigned u; float f; } x; x.u = ((unsigned)h) << 16;
  return x.f;
}

__device__ __forceinline__ void gld16(const void* g, void* l) {
  __builtin_amdgcn_global_load_lds((const __attribute__((address_space(1))) void*)g,
                                   (__attribute__((address_space(3))) void*)l, 16, 0, 0);
}

// ---- A1 prep: x (NHWC f32) -> windowed [25088][1536] bf16 = [Ah | Al | Ah] ----
__global__ __launch_bounds__(256) void k_prep_a1(const float* __restrict__ x, u16* __restrict__ A1) {
  int t = blockIdx.x * 256 + threadIdx.x;
  int r = t >> 6, c8 = (t & 63) << 3;
  int n = r / (P2C * 64); int rem = r - n * (P2C * 64);
  int p = rem >> 6, pix = rem & 63;
  int y = (p / 7) * 8 + (pix >> 3), xx = (p % 7) * 8 + (pix & 7);
  const float* src = x + ((size_t)((n * HH + y) * WWI + xx)) * CDIM + c8;
  float4 v0 = *(const float4*)src, v1 = *(const float4*)(src + 4);
  float vv[8] = {v0.x, v0.y, v0.z, v0.w, v1.x, v1.y, v1.z, v1.w};
  u16x8 Hh, Ll;
#pragma unroll
  for (int i = 0; i < 8; i++) {
    u16 h = f2bf(vv[i]); Hh[i] = h; Ll[i] = f2bf(vv[i] - bf2f(h));
  }
  u16* dst = A1 + (size_t)r * CQKV;
  *(u16x8*)(dst + c8)        = Hh;
  *(u16x8*)(dst + 512 + c8)  = Ll;
  *(u16x8*)(dst + 1024 + c8) = Hh;
}

// ---- weight prep 3-term: [rows][512] f32 -> [rows][1536] bf16 = [Bh | Bh | Bl] ----
__global__ __launch_bounds__(256) void k_prep_b(const float* __restrict__ w, u16* __restrict__ Bq) {
  int t = blockIdx.x * 256 + threadIdx.x;
  int r = t >> 6, c8 = (t & 63) << 3;
  const float* src = w + (size_t)r * CDIM + c8;
  float4 v0 = *(const float4*)src, v1 = *(const float4*)(src + 4);
  float vv[8] = {v0.x, v0.y, v0.z, v0.w, v1.x, v1.y, v1.z, v1.w};
  u16x8 Hh, Ll;
#pragma unroll
  for (int i = 0; i < 8; i++) {
    u16 h = f2bf(vv[i]); Hh[i] = h; Ll[i] = f2bf(vv[i] - bf2f(h));
  }
  u16* dst = Bq + (size_t)r * CQKV;
  *(u16x8*)(dst + c8)        = Hh;
  *(u16x8*)(dst + 512 + c8)  = Hh;
  *(u16x8*)(dst + 1024 + c8) = Ll;
}

// ---- weight prep 2-term (v): qkv_w rows 1024.. -> [512][1024] bf16 = [Bh | Bh] ----
__global__ __launch_bounds__(256) void k_prep_bv(const float* __restrict__ w, u16* __restrict__ Bq) {
  int t = blockIdx.x * 256 + threadIdx.x;
  int r = t >> 6, c8 = (t & 63) << 3;
  const float* src = w + (size_t)(1024 + r) * CDIM + c8;
  float4 v0 = *(const float4*)src, v1 = *(const float4*)(src + 4);
  float vv[8] = {v0.x, v0.y, v0.z, v0.w, v1.x, v1.y, v1.z, v1.w};
  u16x8 Hh;
#pragma unroll
  for (int i = 0; i < 8; i++) Hh[i] = f2bf(vv[i]);
  u16* dst = Bq + (size_t)r * 1024;
  *(u16x8*)(dst + c8)       = Hh;
  *(u16x8*)(dst + 512 + c8) = Hh;
}

// ---- GEMM -> bf16 qkvh slab (optional window-mean epilogue for routing) ----
__global__ __launch_bounds__(256) void k_gemm_h(const u16* __restrict__ A, int lda,
                                                const u16* __restrict__ B, int ldb, int K, int nbn,
                                                const float* __restrict__ bias,
                                                u16* __restrict__ qkvh, int coloff,
                                                float* __restrict__ qw, float* __restrict__ kw) {
  __shared__ u16 As[128 * 32];
  __shared__ u16 Bs[128 * 32];
  int bx = blockIdx.x % nbn, by = blockIdx.x / nbn;
  int tid = threadIdx.x, lane = tid & 63, wid = tid >> 6;
  int wr = (wid >> 1) << 6, wc = (wid & 1) << 6;
  int l15 = lane & 15, h4 = lane >> 4;
  int ar0 = tid >> 2, ac0 = (tid & 3) << 3;
  const u16* Ab = A + (size_t)(by << 7) * lda;
  const u16* Bb = B + (size_t)(bx << 7) * ldb;
  f32x4 acc[4][4] = {};
  for (int k0 = 0; k0 < K; k0 += 32) {
    gld16(Ab + (size_t)ar0 * lda + k0 + ac0,        (char*)As + tid * 16);
    gld16(Ab + (size_t)(ar0 + 64) * lda + k0 + ac0, (char*)As + 4096 + tid * 16);
    gld16(Bb + (size_t)ar0 * ldb + k0 + ac0,        (char*)Bs + tid * 16);
    gld16(Bb + (size_t)(ar0 + 64) * ldb + k0 + ac0, (char*)Bs + 4096 + tid * 16);
    __syncthreads();
    s16x8 af[4], bfr[4];
#pragma unroll
    for (int f = 0; f < 4; f++) af[f]  = *(const s16x8*)((const char*)As + (wr + f * 16 + l15) * 64 + h4 * 16);
#pragma unroll
    for (int f = 0; f < 4; f++) bfr[f] = *(const s16x8*)((const char*)Bs + (wc + f * 16 + l15) * 64 + h4 * 16);
#pragma unroll
    for (int i = 0; i < 4; i++)
#pragma unroll
      for (int j = 0; j < 4; j++)
        acc[i][j] = __builtin_amdgcn_mfma_f32_16x16x32_bf16(af[i], bfr[j], acc[i][j], 0, 0, 0);
    __syncthreads();
  }
#pragma unroll
  for (int i = 0; i < 4; i++) {
#pragma unroll
    for (int j = 0; j < 4; j++) {
      int col = (bx << 7) + wc + j * 16 + l15;
      float bcol = bias[col];
#pragma unroll
      for (int rg = 0; rg < 4; rg++) {
        int row = (by << 7) + wr + i * 16 + h4 * 4 + rg;
        qkvh[(size_t)row * CQKV + coloff + col] = f2bf(acc[i][j][rg] + bcol);
      }
    }
  }
  if (qw) {   // window means from f32 accumulators (routing precision)
    int np = (by << 1) + (wr >> 6);
#pragma unroll
    for (int j = 0; j < 4; j++) {
      float s = 0.f;
#pragma unroll
      for (int i = 0; i < 4; i++)
#pragma unroll
        for (int rg = 0; rg < 4; rg++) s += acc[i][j][rg];
      s += __shfl_xor(s, 16);
      s += __shfl_xor(s, 32);
      int col = (bx << 7) + wc + j * 16 + l15;
      if (h4 == 0) {
        float mv = s * (1.f / 64.f) + bias[col];
        if (col < 512) qw[(size_t)np * 512 + col] = mv;
        else           kw[(size_t)np * 512 + (col - 512)] = mv;
      }
    }
  }
}

// ---- GEMM2: C(f32, spatial layout) = A2 @ B2^T + bias ----
__global__ __launch_bounds__(256) void k_gemm_out(const u16* __restrict__ A, const u16* __restrict__ B,
                                                  float* __restrict__ C, const float* __restrict__ bias) {
  __shared__ u16 As[128 * 32];
  __shared__ u16 Bs[128 * 32];
  const int K = CQKV, N = CDIM;
  int bx = blockIdx.x & 3, by = blockIdx.x >> 2;
  int tid = threadIdx.x, lane = tid & 63, wid = tid >> 6;
  int wr = (wid >> 1) << 6, wc = (wid & 1) << 6;
  int l15 = lane & 15, h4 = lane >> 4;
  int ar0 = tid >> 2, ac0 = (tid & 3) << 3;
  const u16* Ab = A + (size_t)(by << 7) * K;
  const u16* Bb = B + (size_t)(bx << 7) * K;
  f32x4 acc[4][4] = {};
  for (int k0 = 0; k0 < K; k0 += 32) {
    gld16(Ab + (size_t)ar0 * K + k0 + ac0,        (char*)As + tid * 16);
    gld16(Ab + (size_t)(ar0 + 64) * K + k0 + ac0, (char*)As + 4096 + tid * 16);
    gld16(Bb + (size_t)ar0 * K + k0 + ac0,        (char*)Bs + tid * 16);
    gld16(Bb + (size_t)(ar0 + 64) * K + k0 + ac0, (char*)Bs + 4096 + tid * 16);
    __syncthreads();
    s16x8 af[4], bfr[4];
#pragma unroll
    for (int f = 0; f < 4; f++) af[f]  = *(const s16x8*)((const char*)As + (wr + f * 16 + l15) * 64 + h4 * 16);
#pragma unroll
    for (int f = 0; f < 4; f++) bfr[f] = *(const s16x8*)((const char*)Bs + (wc + f * 16 + l15) * 64 + h4 * 16);
#pragma unroll
    for (int i = 0; i < 4; i++)
#pragma unroll
      for (int j = 0; j < 4; j++)
        acc[i][j] = __builtin_amdgcn_mfma_f32_16x16x32_bf16(af[i], bfr[j], acc[i][j], 0, 0, 0);
    __syncthreads();
  }
#pragma unroll
  for (int i = 0; i < 4; i++) {
#pragma unroll
    for (int j = 0; j < 4; j++) {
      int col = (bx << 7) + wc + j * 16 + l15;
      float bcol = bias[col];
#pragma unroll
      for (int rg = 0; rg < 4; rg++) {
        int row = (by << 7) + wr + i * 16 + h4 * 4 + rg;
        int n = row / (P2C * 64); int rem = row - n * (P2C * 64);
        int p = rem >> 6, pix = rem & 63;
        int y = (p / 7) * 8 + (pix >> 3), xx = (p % 7) * 8 + (pix & 7);
        C[(size_t)((n * HH + y) * WWI + xx) * N + col] = acc[i][j][rg] + bcol;
      }
    }
  }
}

// ---- routing: per (n,p) 49 logits from f32 window means, top-4 (stable ties) ----
__global__ __launch_bounds__(64) void k_route(const float* __restrict__ qw,
                                              const float* __restrict__ kw, int* __restrict__ ridx) {
  int np = blockIdx.x, n = np / P2C;
  int t = threadIdx.x;
  __shared__ float qrow[512];
  __shared__ float logit[64];
  for (int c = t; c < 512; c += 64) qrow[c] = qw[(size_t)np * 512 + c];
  __syncthreads();
  if (t < P2C) {
    const float* kr = kw + (size_t)(n * P2C + t) * 512;
    float s = 0.f;
    for (int c = 0; c < 512; c++) s += qrow[c] * kr[c];
    logit[t] = s;
  }
  __syncthreads();
  if (t == 0) {
    for (int tt = 0; tt < 4; tt++) {
      float best = -1e30f; int bi = 0;
      for (int q = 0; q < P2C; q++) if (logit[q] > best) { best = logit[q]; bi = q; }
      ridx[np * 4 + tt] = bi;
      logit[bi] = -1e30f;
    }
  }
}

// ---- LePE depthwise 3x3 (zero pad) on v (bf16 in qkvh), bf16 out, windowed rows ----
__global__ __launch_bounds__(256) void k_lepe(const u16* __restrict__ qkvh,
                                              const float* __restrict__ lw, const float* __restrict__ lb,
                                              u16* __restrict__ lepe) {
  int t = blockIdx.x * 256 + threadIdx.x;
  int r = t >> 6, c8 = (t & 63) << 3;
  int n = r / (P2C * 64); int rem = r - n * (P2C * 64);
  int p = rem >> 6, pix = rem & 63;
  int y = (p / 7) * 8 + (pix >> 3), xx = (p % 7) * 8 + (pix & 7);
  float acc[8];
#pragma unroll
  for (int i = 0; i < 8; i++) acc[i] = lb[c8 + i];
#pragma unroll
  for (int dy = -1; dy <= 1; dy++) {
#pragma unroll
    for (int dx = -1; dx <= 1; dx++) {
      int yy = y + dy, xz = xx + dx;
      if (yy < 0 || yy >= HH || xz < 0 || xz >= WWI) continue;
      int p2 = (yy >> 3) * 7 + (xz >> 3), px2 = (yy & 7) * 8 + (xz & 7);
      const u16* v = qkvh + ((size_t)((n * P2C + p2) * 64 + px2)) * CQKV + 1024 + c8;
      u16x8 a = *(const u16x8*)v;
#pragma unroll
      for (int i = 0; i < 8; i++) acc[i] += bf2f(a[i]) * lw[(c8 + i) * 9 + (dy + 1) * 3 + (dx + 1)];
    }
  }
  u16x8 o;
#pragma unroll
  for (int i = 0; i < 8; i++) o[i] = f2bf(acc[i]);
  *(u16x8*)(lepe + (size_t)r * CDIM + c8) = o;
}

// ---- attention: block=(np, head-quad), wave=head. Swapped S^T=K*Q^T, in-reg softmax, PV.
//      V fragments hoisted (fq-independent). Epilogue: + lepe, write A2 [hi|lo|hi].
__global__ __launch_bounds__(256) void k_attn(const u16* __restrict__ qkvh,
                                              const int* __restrict__ ridx,
                                              const u16* __restrict__ lepe, u16* __restrict__ A2) {
  int b = blockIdx.x;
  int mq = b & 3, np = b >> 2;
  int n = np / P2C;
  int wid = threadIdx.x >> 6, lane = threadIdx.x & 63;
  int m = (mq << 2) + wid;
  int l15 = lane & 15, h4 = lane >> 4;
  size_t krow0[4];
#pragma unroll
  for (int w = 0; w < 4; w++) krow0[w] = (size_t)(n * P2C + ridx[np * 4 + w]) * 64;
  size_t qrow0 = (size_t)np * 64;
  union FR { s16x8 s; u16 u[8]; };
  f32x4 zero = {0.f, 0.f, 0.f, 0.f};
  FR qf[4];
#pragma unroll
  for (int fq = 0; fq < 4; fq++)
    qf[fq].s = *(const s16x8*)(qkvh + (qrow0 + fq * 16 + l15) * CQKV + m * 32 + h4 * 8);
  // hoisted V fragments (fq-independent): vf[s8][fd]
  FR vf[8][2];
#pragma unroll
  for (int s8 = 0; s8 < 8; s8++)
#pragma unroll
    for (int fd = 0; fd < 2; fd++)
#pragma unroll
      for (int jj = 0; jj < 8; jj++) {
        int key = 32 * s8 + h4 * 4 + (jj & 3) + ((jj >> 2) << 4);
        vf[s8][fd].u[jj] = qkvh[(krow0[key >> 6] + (key & 63)) * CQKV + 1024 + m * 32 + fd * 16 + l15];
      }
#pragma unroll
  for (int fq = 0; fq < 4; fq++) {
    f32x4 st[16];
#pragma unroll
    for (int fk = 0; fk < 16; fk++) {
      int key = fk * 16 + l15;
      FR kf;
      kf.s = *(const s16x8*)(qkvh + (krow0[key >> 6] + (key & 63)) * CQKV + 512 + m * 32 + h4 * 8);
      st[fk] = __builtin_amdgcn_mfma_f32_16x16x32_bf16(kf.s, qf[fq].s, zero, 0, 0, 0);
    }
    float mx = -1e30f;
#pragma unroll
    for (int fk = 0; fk < 16; fk++)
#pragma unroll
      for (int rg = 0; rg < 4; rg++) {
        float v = st[fk][rg] * SCALE_F; st[fk][rg] = v; mx = fmaxf(mx, v);
      }
    mx = fmaxf(mx, __shfl_xor(mx, 16));
    mx = fmaxf(mx, __shfl_xor(mx, 32));
    float sum = 0.f;
#pragma unroll
    for (int fk = 0; fk < 16; fk++)
#pragma unroll
      for (int rg = 0; rg < 4; rg++) {
        float e = __expf(st[fk][rg] - mx); st[fk][rg] = e; sum += e;
      }
    sum += __shfl_xor(sum, 16);
    sum += __shfl_xor(sum, 32);
    f32x4 oacc[2] = {zero, zero};
#pragma unroll
    for (int s8 = 0; s8 < 8; s8++) {
      FR pa;
#pragma unroll
      for (int jj = 0; jj < 8; jj++) pa.u[jj] = f2bf(st[2 * s8 + (jj >> 2)][jj & 3]);
#pragma unroll
      for (int fd = 0; fd < 2; fd++)
        oacc[fd] = __builtin_amdgcn_mfma_f32_16x16x32_bf16(pa.s, vf[s8][fd].s, oacc[fd], 0, 0, 0);
    }
#pragma unroll
    for (int rg = 0; rg < 4; rg++) {
      float sq = __shfl(sum, h4 * 4 + rg);
      int q = fq * 16 + h4 * 4 + rg;
#pragma unroll
      for (int fd = 0; fd < 2; fd++) {
        int col = m * 32 + fd * 16 + l15;
        size_t row = qrow0 + q;
        float val = oacc[fd][rg] / sq + bf2f(lepe[row * CDIM + col]);
        u16 hi = f2bf(val);
        u16 lo = f2bf(val - bf2f(hi));
        A2[row * CQKV + col]        = hi;
        A2[row * CQKV + 512 + col]  = lo;
        A2[row * CQKV + 1024 + col] = hi;
      }
    }
  }
}

extern "C" void kernel_launch(void* const* d_in, const int* in_sizes, int n_in,
                              void* d_out, int out_size, void* d_ws, size_t ws_size,
                              hipStream_t stream) {
  (void)in_sizes; (void)n_in; (void)out_size; (void)ws_size;
  const float* x      = (const float*)d_in[0];
  const float* qkv_w  = (const float*)d_in[1];
  const float* qkv_b  = (const float*)d_in[2];
  const float* wo_w   = (const float*)d_in[3];
  const float* wo_b   = (const float*)d_in[4];
  const float* lepe_w = (const float*)d_in[5];
  const float* lepe_b = (const float*)d_in[6];
  float* out = (float*)d_out;
  char* ws = (char*)d_ws;
  size_t off = 0;
  auto alc = [&](size_t b) { char* p = ws + off; off += (b + 255) & ~(size_t)255; return p; };
  u16*   B1    = (u16*)  alc((size_t)1024 * CQKV * 2);        //  3.1 MB  (q,k rows, 3-term)
  u16*   Bv    = (u16*)  alc((size_t)512 * 1024 * 2);         //  1.0 MB  (v rows, 2-term)
  u16*   B2    = (u16*)  alc((size_t)CDIM * CQKV * 2);        //  1.6 MB
  u16*   qkvh  = (u16*)  alc((size_t)NROWS * CQKV * 2);       // 77.1 MB
  float* qw    = (float*)alc((size_t)NB * P2C * CDIM * 4);    //  0.8 MB
  float* kw    = (float*)alc((size_t)NB * P2C * CDIM * 4);    //  0.8 MB
  int*   ridx  = (int*)  alc((size_t)NB * P2C * 4 * 4);       //  6 KB
  u16*   lepe  = (u16*)  alc((size_t)NROWS * CDIM * 2);       // 25.7 MB
  u16*   A12   = (u16*)  alc((size_t)NROWS * CQKV * 2);       // 77.1 MB (A1, later A2)
  // total ~187 MB

  k_prep_a1<<<dim3(6272), dim3(256), 0, stream>>>(x, A12);
  k_prep_b <<<dim3(256),  dim3(256), 0, stream>>>(qkv_w, B1);     // rows 0..1023 (q,k)
  k_prep_bv<<<dim3(128),  dim3(256), 0, stream>>>(qkv_w, Bv);     // rows 1024..1535 (v)
  k_prep_b <<<dim3(128),  dim3(256), 0, stream>>>(wo_w, B2);
  k_gemm_h <<<dim3(1568), dim3(256), 0, stream>>>(A12, CQKV, B1, CQKV, CQKV, 8,
                                                  qkv_b, qkvh, 0, qw, kw);
  k_gemm_h <<<dim3(784),  dim3(256), 0, stream>>>(A12, CQKV, Bv, 1024, 1024, 4,
                                                  qkv_b + 1024, qkvh, 1024, nullptr, nullptr);
  k_route <<<dim3(392),  dim3(64),  0, stream>>>(qw, kw, ridx);
  k_lepe  <<<dim3(6272), dim3(256), 0, stream>>>(qkvh, lepe_w, lepe_b, lepe);
  k_attn  <<<dim3(1568), dim3(256), 0, stream>>>(qkvh, ridx, lepe, A12);
  k_gemm_out<<<dim3(784), dim3(256), 0, stream>>>(A12, B2, out, wo_b);
}

// Round 4
// 556.293 us; speedup vs baseline: 1.3130x; 1.3130x over previous
//
#include <hip/hip_runtime.h>

typedef unsigned short u16;
typedef __attribute__((ext_vector_type(8))) short  s16x8;
typedef __attribute__((ext_vector_type(8))) u16    u16x8;
typedef __attribute__((ext_vector_type(4))) float  f32x4;

#define NB    8
#define HH    56
#define WWI   56
#define CDIM  512
#define CQKV  1536
#define P2C   49
#define NROWS (NB*P2C*64)      // 25088 windowed pixel rows
#define SCALE_F 0.04419417382415922f

__device__ __forceinline__ u16 f2bf(float f) {
  union { float f; unsigned u; } x; x.f = f;
  unsigned r = x.u + 0x7fffu + ((x.u >> 16) & 1u);
  return (u16)(r >> 16);
}
__device__ __forceinline__ float bf2f(u16 h) {
  union { unsigned u; float f; } x; x.u = ((unsigned)h) << 16;
  return x.f;
}

__device__ __forceinline__ void gld16(const void* g, void* l) {
  __builtin_amdgcn_global_load_lds((const __attribute__((address_space(1))) void*)g,
                                   (__attribute__((address_space(3))) void*)l, 16, 0, 0);
}

// ---- A1 prep: x (NHWC f32) -> windowed [25088][1536] bf16 = [Ah | Al | Ah] ----
__global__ __launch_bounds__(256) void k_prep_a1(const float* __restrict__ x, u16* __restrict__ A1) {
  int t = blockIdx.x * 256 + threadIdx.x;
  int r = t >> 6, c8 = (t & 63) << 3;
  int n = r / (P2C * 64); int rem = r - n * (P2C * 64);
  int p = rem >> 6, pix = rem & 63;
  int y = (p / 7) * 8 + (pix >> 3), xx = (p % 7) * 8 + (pix & 7);
  const float* src = x + ((size_t)((n * HH + y) * WWI + xx)) * CDIM + c8;
  float4 v0 = *(const float4*)src, v1 = *(const float4*)(src + 4);
  float vv[8] = {v0.x, v0.y, v0.z, v0.w, v1.x, v1.y, v1.z, v1.w};
  u16x8 Hh, Ll;
#pragma unroll
  for (int i = 0; i < 8; i++) {
    u16 h = f2bf(vv[i]); Hh[i] = h; Ll[i] = f2bf(vv[i] - bf2f(h));
  }
  u16* dst = A1 + (size_t)r * CQKV;
  *(u16x8*)(dst + c8)        = Hh;
  *(u16x8*)(dst + 512 + c8)  = Ll;
  *(u16x8*)(dst + 1024 + c8) = Hh;
}

// ---- weight prep 3-term: [rows][512] f32 -> [rows][1536] bf16 = [Bh | Bh | Bl] ----
__global__ __launch_bounds__(256) void k_prep_b(const float* __restrict__ w, u16* __restrict__ Bq) {
  int t = blockIdx.x * 256 + threadIdx.x;
  int r = t >> 6, c8 = (t & 63) << 3;
  const float* src = w + (size_t)r * CDIM + c8;
  float4 v0 = *(const float4*)src, v1 = *(const float4*)(src + 4);
  float vv[8] = {v0.x, v0.y, v0.z, v0.w, v1.x, v1.y, v1.z, v1.w};
  u16x8 Hh, Ll;
#pragma unroll
  for (int i = 0; i < 8; i++) {
    u16 h = f2bf(vv[i]); Hh[i] = h; Ll[i] = f2bf(vv[i] - bf2f(h));
  }
  u16* dst = Bq + (size_t)r * CQKV;
  *(u16x8*)(dst + c8)        = Hh;
  *(u16x8*)(dst + 512 + c8)  = Hh;
  *(u16x8*)(dst + 1024 + c8) = Ll;
}

// ---- weight prep 2-term (v): qkv_w rows 1024.. -> [512][1024] bf16 = [Bh | Bh] ----
__global__ __launch_bounds__(256) void k_prep_bv(const float* __restrict__ w, u16* __restrict__ Bq) {
  int t = blockIdx.x * 256 + threadIdx.x;
  int r = t >> 6, c8 = (t & 63) << 3;
  const float* src = w + (size_t)(1024 + r) * CDIM + c8;
  float4 v0 = *(const float4*)src, v1 = *(const float4*)(src + 4);
  float vv[8] = {v0.x, v0.y, v0.z, v0.w, v1.x, v1.y, v1.z, v1.w};
  u16x8 Hh;
#pragma unroll
  for (int i = 0; i < 8; i++) Hh[i] = f2bf(vv[i]);
  u16* dst = Bq + (size_t)r * 1024;
  *(u16x8*)(dst + c8)       = Hh;
  *(u16x8*)(dst + 512 + c8) = Hh;
}

// ---- LePE weight transpose: lepe_w [512][9] f32 -> lwt [9][512] f32 ----
__global__ __launch_bounds__(256) void k_prep_lw(const float* __restrict__ lw, float* __restrict__ lwt) {
  int idx = blockIdx.x * 256 + threadIdx.x;   // 0..4607
  int tap = idx >> 9, ch = idx & 511;
  lwt[idx] = lw[ch * 9 + tap];
}

// ---- GEMM -> bf16 qkvh slab (optional window-mean epilogue for routing) ----
__global__ __launch_bounds__(256) void k_gemm_h(const u16* __restrict__ A, int lda,
                                                const u16* __restrict__ B, int ldb, int K, int nbn,
                                                const float* __restrict__ bias,
                                                u16* __restrict__ qkvh, int coloff,
                                                float* __restrict__ qw, float* __restrict__ kw) {
  __shared__ u16 As[128 * 32];
  __shared__ u16 Bs[128 * 32];
  int bx = blockIdx.x % nbn, by = blockIdx.x / nbn;
  int tid = threadIdx.x, lane = tid & 63, wid = tid >> 6;
  int wr = (wid >> 1) << 6, wc = (wid & 1) << 6;
  int l15 = lane & 15, h4 = lane >> 4;
  int ar0 = tid >> 2, ac0 = (tid & 3) << 3;
  const u16* Ab = A + (size_t)(by << 7) * lda;
  const u16* Bb = B + (size_t)(bx << 7) * ldb;
  f32x4 acc[4][4] = {};
  for (int k0 = 0; k0 < K; k0 += 32) {
    gld16(Ab + (size_t)ar0 * lda + k0 + ac0,        (char*)As + tid * 16);
    gld16(Ab + (size_t)(ar0 + 64) * lda + k0 + ac0, (char*)As + 4096 + tid * 16);
    gld16(Bb + (size_t)ar0 * ldb + k0 + ac0,        (char*)Bs + tid * 16);
    gld16(Bb + (size_t)(ar0 + 64) * ldb + k0 + ac0, (char*)Bs + 4096 + tid * 16);
    __syncthreads();
    s16x8 af[4], bfr[4];
#pragma unroll
    for (int f = 0; f < 4; f++) af[f]  = *(const s16x8*)((const char*)As + (wr + f * 16 + l15) * 64 + h4 * 16);
#pragma unroll
    for (int f = 0; f < 4; f++) bfr[f] = *(const s16x8*)((const char*)Bs + (wc + f * 16 + l15) * 64 + h4 * 16);
#pragma unroll
    for (int i = 0; i < 4; i++)
#pragma unroll
      for (int j = 0; j < 4; j++)
        acc[i][j] = __builtin_amdgcn_mfma_f32_16x16x32_bf16(af[i], bfr[j], acc[i][j], 0, 0, 0);
    __syncthreads();
  }
#pragma unroll
  for (int i = 0; i < 4; i++) {
#pragma unroll
    for (int j = 0; j < 4; j++) {
      int col = (bx << 7) + wc + j * 16 + l15;
      float bcol = bias[col];
#pragma unroll
      for (int rg = 0; rg < 4; rg++) {
        int row = (by << 7) + wr + i * 16 + h4 * 4 + rg;
        qkvh[(size_t)row * CQKV + coloff + col] = f2bf(acc[i][j][rg] + bcol);
      }
    }
  }
  if (qw) {   // window means from f32 accumulators (routing precision)
    int np = (by << 1) + (wr >> 6);
#pragma unroll
    for (int j = 0; j < 4; j++) {
      float s = 0.f;
#pragma unroll
      for (int i = 0; i < 4; i++)
#pragma unroll
        for (int rg = 0; rg < 4; rg++) s += acc[i][j][rg];
      s += __shfl_xor(s, 16);
      s += __shfl_xor(s, 32);
      int col = (bx << 7) + wc + j * 16 + l15;
      if (h4 == 0) {
        float mv = s * (1.f / 64.f) + bias[col];
        if (col < 512) qw[(size_t)np * 512 + col] = mv;
        else           kw[(size_t)np * 512 + (col - 512)] = mv;
      }
    }
  }
}

// ---- GEMM2: C(f32, spatial layout) = A2 @ B2^T + bias ----
__global__ __launch_bounds__(256) void k_gemm_out(const u16* __restrict__ A, const u16* __restrict__ B,
                                                  float* __restrict__ C, const float* __restrict__ bias) {
  __shared__ u16 As[128 * 32];
  __shared__ u16 Bs[128 * 32];
  const int K = CQKV, N = CDIM;
  int bx = blockIdx.x & 3, by = blockIdx.x >> 2;
  int tid = threadIdx.x, lane = tid & 63, wid = tid >> 6;
  int wr = (wid >> 1) << 6, wc = (wid & 1) << 6;
  int l15 = lane & 15, h4 = lane >> 4;
  int ar0 = tid >> 2, ac0 = (tid & 3) << 3;
  const u16* Ab = A + (size_t)(by << 7) * K;
  const u16* Bb = B + (size_t)(bx << 7) * K;
  f32x4 acc[4][4] = {};
  for (int k0 = 0; k0 < K; k0 += 32) {
    gld16(Ab + (size_t)ar0 * K + k0 + ac0,        (char*)As + tid * 16);
    gld16(Ab + (size_t)(ar0 + 64) * K + k0 + ac0, (char*)As + 4096 + tid * 16);
    gld16(Bb + (size_t)ar0 * K + k0 + ac0,        (char*)Bs + tid * 16);
    gld16(Bb + (size_t)(ar0 + 64) * K + k0 + ac0, (char*)Bs + 4096 + tid * 16);
    __syncthreads();
    s16x8 af[4], bfr[4];
#pragma unroll
    for (int f = 0; f < 4; f++) af[f]  = *(const s16x8*)((const char*)As + (wr + f * 16 + l15) * 64 + h4 * 16);
#pragma unroll
    for (int f = 0; f < 4; f++) bfr[f] = *(const s16x8*)((const char*)Bs + (wc + f * 16 + l15) * 64 + h4 * 16);
#pragma unroll
    for (int i = 0; i < 4; i++)
#pragma unroll
      for (int j = 0; j < 4; j++)
        acc[i][j] = __builtin_amdgcn_mfma_f32_16x16x32_bf16(af[i], bfr[j], acc[i][j], 0, 0, 0);
    __syncthreads();
  }
#pragma unroll
  for (int i = 0; i < 4; i++) {
#pragma unroll
    for (int j = 0; j < 4; j++) {
      int col = (bx << 7) + wc + j * 16 + l15;
      float bcol = bias[col];
#pragma unroll
      for (int rg = 0; rg < 4; rg++) {
        int row = (by << 7) + wr + i * 16 + h4 * 4 + rg;
        int n = row / (P2C * 64); int rem = row - n * (P2C * 64);
        int p = rem >> 6, pix = rem & 63;
        int y = (p / 7) * 8 + (pix >> 3), xx = (p % 7) * 8 + (pix & 7);
        C[(size_t)((n * HH + y) * WWI + xx) * N + col] = acc[i][j][rg] + bcol;
      }
    }
  }
}

// ---- routing: per (n,p) 49 logits from f32 window means, top-4 (stable ties) ----
__global__ __launch_bounds__(64) void k_route(const float* __restrict__ qw,
                                              const float* __restrict__ kw, int* __restrict__ ridx) {
  int np = blockIdx.x, n = np / P2C;
  int t = threadIdx.x;
  __shared__ float qrow[512];
  __shared__ float logit[64];
  for (int c = t; c < 512; c += 64) qrow[c] = qw[(size_t)np * 512 + c];
  __syncthreads();
  if (t < P2C) {
    const float* kr = kw + (size_t)(n * P2C + t) * 512;
    float s = 0.f;
    for (int c = 0; c < 512; c++) s += qrow[c] * kr[c];
    logit[t] = s;
  }
  __syncthreads();
  if (t == 0) {
    for (int tt = 0; tt < 4; tt++) {
      float best = -1e30f; int bi = 0;
      for (int q = 0; q < P2C; q++) if (logit[q] > best) { best = logit[q]; bi = q; }
      ridx[np * 4 + tt] = bi;
      logit[bi] = -1e30f;
    }
  }
}

// ---- LePE depthwise 3x3 (zero pad), transposed weights lwt[9][512] (coalesced) ----
__global__ __launch_bounds__(256) void k_lepe(const u16* __restrict__ qkvh,
                                              const float* __restrict__ lwt, const float* __restrict__ lb,
                                              u16* __restrict__ lepe) {
  int t = blockIdx.x * 256 + threadIdx.x;
  int r = t >> 6, c8 = (t & 63) << 3;
  int n = r / (P2C * 64); int rem = r - n * (P2C * 64);
  int p = rem >> 6, pix = rem & 63;
  int y = (p / 7) * 8 + (pix >> 3), xx = (p % 7) * 8 + (pix & 7);
  float acc[8];
  {
    float4 b0 = *(const float4*)(lb + c8), b1 = *(const float4*)(lb + c8 + 4);
    acc[0]=b0.x; acc[1]=b0.y; acc[2]=b0.z; acc[3]=b0.w;
    acc[4]=b1.x; acc[5]=b1.y; acc[6]=b1.z; acc[7]=b1.w;
  }
#pragma unroll
  for (int dy = -1; dy <= 1; dy++) {
#pragma unroll
    for (int dx = -1; dx <= 1; dx++) {
      int yy = y + dy, xz = xx + dx;
      if (yy < 0 || yy >= HH || xz < 0 || xz >= WWI) continue;
      int tap = (dy + 1) * 3 + (dx + 1);
      int p2 = (yy >> 3) * 7 + (xz >> 3), px2 = (yy & 7) * 8 + (xz & 7);
      const u16* v = qkvh + ((size_t)((n * P2C + p2) * 64 + px2)) * CQKV + 1024 + c8;
      u16x8 a = *(const u16x8*)v;
      const float* wrow = lwt + tap * 512 + c8;
      float4 w0 = *(const float4*)wrow, w1 = *(const float4*)(wrow + 4);
      float ww[8] = {w0.x, w0.y, w0.z, w0.w, w1.x, w1.y, w1.z, w1.w};
#pragma unroll
      for (int i = 0; i < 8; i++) acc[i] += bf2f(a[i]) * ww[i];
    }
  }
  u16x8 o;
#pragma unroll
  for (int i = 0; i < 8; i++) o[i] = f2bf(acc[i]);
  *(u16x8*)(lepe + (size_t)r * CDIM + c8) = o;
}

// ---- attention: block=(np, head-quad), wave=head. Swapped S^T=K*Q^T, in-reg softmax, PV.
//      V fragments hoisted (fq-independent). Epilogue: + lepe, write A2 [hi|lo|hi].
__global__ __launch_bounds__(256) void k_attn(const u16* __restrict__ qkvh,
                                              const int* __restrict__ ridx,
                                              const u16* __restrict__ lepe, u16* __restrict__ A2) {
  int b = blockIdx.x;
  int mq = b & 3, np = b >> 2;
  int n = np / P2C;
  int wid = threadIdx.x >> 6, lane = threadIdx.x & 63;
  int m = (mq << 2) + wid;
  int l15 = lane & 15, h4 = lane >> 4;
  size_t krow0[4];
#pragma unroll
  for (int w = 0; w < 4; w++) krow0[w] = (size_t)(n * P2C + ridx[np * 4 + w]) * 64;
  size_t qrow0 = (size_t)np * 64;
  union FR { s16x8 s; u16 u[8]; };
  f32x4 zero = {0.f, 0.f, 0.f, 0.f};
  FR qf[4];
#pragma unroll
  for (int fq = 0; fq < 4; fq++)
    qf[fq].s = *(const s16x8*)(qkvh + (qrow0 + fq * 16 + l15) * CQKV + m * 32 + h4 * 8);
  // hoisted V fragments (fq-independent): vf[s8][fd]
  FR vf[8][2];
#pragma unroll
  for (int s8 = 0; s8 < 8; s8++)
#pragma unroll
    for (int fd = 0; fd < 2; fd++)
#pragma unroll
      for (int jj = 0; jj < 8; jj++) {
        int key = 32 * s8 + h4 * 4 + (jj & 3) + ((jj >> 2) << 4);
        vf[s8][fd].u[jj] = qkvh[(krow0[key >> 6] + (key & 63)) * CQKV + 1024 + m * 32 + fd * 16 + l15];
      }
#pragma unroll
  for (int fq = 0; fq < 4; fq++) {
    f32x4 st[16];
#pragma unroll
    for (int fk = 0; fk < 16; fk++) {
      int key = fk * 16 + l15;
      FR kf;
      kf.s = *(const s16x8*)(qkvh + (krow0[key >> 6] + (key & 63)) * CQKV + 512 + m * 32 + h4 * 8);
      st[fk] = __builtin_amdgcn_mfma_f32_16x16x32_bf16(kf.s, qf[fq].s, zero, 0, 0, 0);
    }
    float mx = -1e30f;
#pragma unroll
    for (int fk = 0; fk < 16; fk++)
#pragma unroll
      for (int rg = 0; rg < 4; rg++) {
        float v = st[fk][rg] * SCALE_F; st[fk][rg] = v; mx = fmaxf(mx, v);
      }
    mx = fmaxf(mx, __shfl_xor(mx, 16));
    mx = fmaxf(mx, __shfl_xor(mx, 32));
    float sum = 0.f;
#pragma unroll
    for (int fk = 0; fk < 16; fk++)
#pragma unroll
      for (int rg = 0; rg < 4; rg++) {
        float e = __expf(st[fk][rg] - mx); st[fk][rg] = e; sum += e;
      }
    sum += __shfl_xor(sum, 16);
    sum += __shfl_xor(sum, 32);
    f32x4 oacc[2] = {zero, zero};
#pragma unroll
    for (int s8 = 0; s8 < 8; s8++) {
      FR pa;
#pragma unroll
      for (int jj = 0; jj < 8; jj++) pa.u[jj] = f2bf(st[2 * s8 + (jj >> 2)][jj & 3]);
#pragma unroll
      for (int fd = 0; fd < 2; fd++)
        oacc[fd] = __builtin_amdgcn_mfma_f32_16x16x32_bf16(pa.s, vf[s8][fd].s, oacc[fd], 0, 0, 0);
    }
#pragma unroll
    for (int rg = 0; rg < 4; rg++) {
      float sq = __shfl(sum, h4 * 4 + rg);
      int q = fq * 16 + h4 * 4 + rg;
#pragma unroll
      for (int fd = 0; fd < 2; fd++) {
        int col = m * 32 + fd * 16 + l15;
        size_t row = qrow0 + q;
        float val = oacc[fd][rg] / sq + bf2f(lepe[row * CDIM + col]);
        u16 hi = f2bf(val);
        u16 lo = f2bf(val - bf2f(hi));
        A2[row * CQKV + col]        = hi;
        A2[row * CQKV + 512 + col]  = lo;
        A2[row * CQKV + 1024 + col] = hi;
      }
    }
  }
}

extern "C" void kernel_launch(void* const* d_in, const int* in_sizes, int n_in,
                              void* d_out, int out_size, void* d_ws, size_t ws_size,
                              hipStream_t stream) {
  (void)in_sizes; (void)n_in; (void)out_size; (void)ws_size;
  const float* x      = (const float*)d_in[0];
  const float* qkv_w  = (const float*)d_in[1];
  const float* qkv_b  = (const float*)d_in[2];
  const float* wo_w   = (const float*)d_in[3];
  const float* wo_b   = (const float*)d_in[4];
  const float* lepe_w = (const float*)d_in[5];
  const float* lepe_b = (const float*)d_in[6];
  float* out = (float*)d_out;
  char* ws = (char*)d_ws;
  size_t off = 0;
  auto alc = [&](size_t b) { char* p = ws + off; off += (b + 255) & ~(size_t)255; return p; };
  u16*   B1    = (u16*)  alc((size_t)1024 * CQKV * 2);        //  3.1 MB  (q,k rows, 3-term)
  u16*   Bv    = (u16*)  alc((size_t)512 * 1024 * 2);         //  1.0 MB  (v rows, 2-term)
  u16*   B2    = (u16*)  alc((size_t)CDIM * CQKV * 2);        //  1.6 MB
  float* lwt   = (float*)alc((size_t)9 * 512 * 4);            //  18 KB   (transposed LePE w)
  u16*   qkvh  = (u16*)  alc((size_t)NROWS * CQKV * 2);       // 77.1 MB
  float* qw    = (float*)alc((size_t)NB * P2C * CDIM * 4);    //  0.8 MB
  float* kw    = (float*)alc((size_t)NB * P2C * CDIM * 4);    //  0.8 MB
  int*   ridx  = (int*)  alc((size_t)NB * P2C * 4 * 4);       //  6 KB
  u16*   lepe  = (u16*)  alc((size_t)NROWS * CDIM * 2);       // 25.7 MB
  u16*   A12   = (u16*)  alc((size_t)NROWS * CQKV * 2);       // 77.1 MB (A1, later A2)
  // total ~187 MB

  k_prep_a1<<<dim3(6272), dim3(256), 0, stream>>>(x, A12);
  k_prep_b <<<dim3(256),  dim3(256), 0, stream>>>(qkv_w, B1);     // rows 0..1023 (q,k)
  k_prep_bv<<<dim3(128),  dim3(256), 0, stream>>>(qkv_w, Bv);     // rows 1024..1535 (v)
  k_prep_b <<<dim3(128),  dim3(256), 0, stream>>>(wo_w, B2);
  k_prep_lw<<<dim3(18),   dim3(256), 0, stream>>>(lepe_w, lwt);
  k_gemm_h <<<dim3(1568), dim3(256), 0, stream>>>(A12, CQKV, B1, CQKV, CQKV, 8,
                                                  qkv_b, qkvh, 0, qw, kw);
  k_gemm_h <<<dim3(784),  dim3(256), 0, stream>>>(A12, CQKV, Bv, 1024, 1024, 4,
                                                  qkv_b + 1024, qkvh, 1024, nullptr, nullptr);
  k_route <<<dim3(392),  dim3(64),  0, stream>>>(qw, kw, ridx);
  k_lepe  <<<dim3(6272), dim3(256), 0, stream>>>(qkvh, lwt, lepe_b, lepe);
  k_attn  <<<dim3(1568), dim3(256), 0, stream>>>(qkvh, ridx, lepe, A12);
  k_gemm_out<<<dim3(784), dim3(256), 0, stream>>>(A12, B2, out, wo_b);
}

// Round 5
// 512.989 us; speedup vs baseline: 1.4239x; 1.0844x over previous
//
#include <hip/hip_runtime.h>

typedef unsigned short u16;
typedef __attribute__((ext_vector_type(8))) short  s16x8;
typedef __attribute__((ext_vector_type(8))) u16    u16x8;
typedef __attribute__((ext_vector_type(4))) u16    u16x4;
typedef __attribute__((ext_vector_type(4))) float  f32x4;

#define NB    8
#define HH    56
#define WWI   56
#define CDIM  512
#define CQKV  1536
#define P2C   49
#define NROWS (NB*P2C*64)      // 25088 windowed pixel rows
// SCALE * log2(e)
#define SC_LOG2E 0.06375871682f

__device__ __forceinline__ u16 f2bf(float f) {
  union { float f; unsigned u; } x; x.f = f;
  unsigned r = x.u + 0x7fffu + ((x.u >> 16) & 1u);
  return (u16)(r >> 16);
}
__device__ __forceinline__ float bf2f(u16 h) {
  union { unsigned u; float f; } x; x.u = ((unsigned)h) << 16;
  return x.f;
}
__device__ __forceinline__ unsigned cvtpk(float lo, float hi) {
  unsigned d;
  asm("v_cvt_pk_bf16_f32 %0, %1, %2" : "=v"(d) : "v"(lo), "v"(hi));
  return d;
}

__device__ __forceinline__ void gld16(const void* g, void* l) {
  __builtin_amdgcn_global_load_lds((const __attribute__((address_space(1))) void*)g,
                                   (__attribute__((address_space(3))) void*)l, 16, 0, 0);
}

// ---- A1 prep: x (NHWC f32) -> windowed [25088][1024] bf16 = [Ah | Al] ----
__global__ __launch_bounds__(256) void k_prep_a1(const float* __restrict__ x, u16* __restrict__ A1) {
  int t = blockIdx.x * 256 + threadIdx.x;
  int r = t >> 6, c8 = (t & 63) << 3;
  int n = r / (P2C * 64); int rem = r - n * (P2C * 64);
  int p = rem >> 6, pix = rem & 63;
  int y = (p / 7) * 8 + (pix >> 3), xx = (p % 7) * 8 + (pix & 7);
  const float* src = x + ((size_t)((n * HH + y) * WWI + xx)) * CDIM + c8;
  float4 v0 = *(const float4*)src, v1 = *(const float4*)(src + 4);
  float vv[8] = {v0.x, v0.y, v0.z, v0.w, v1.x, v1.y, v1.z, v1.w};
  u16x8 Hh, Ll;
#pragma unroll
  for (int i = 0; i < 8; i++) {
    u16 h = f2bf(vv[i]); Hh[i] = h; Ll[i] = f2bf(vv[i] - bf2f(h));
  }
  u16* dst = A1 + (size_t)r * 1024;
  *(u16x8*)(dst + c8)       = Hh;
  *(u16x8*)(dst + 512 + c8) = Ll;
}

// ---- weight prep 3-term: [rows][512] f32 -> [rows][1536] bf16 = [Bh | Bh | Bl] ----
__global__ __launch_bounds__(256) void k_prep_b(const float* __restrict__ w, u16* __restrict__ Bq) {
  int t = blockIdx.x * 256 + threadIdx.x;
  int r = t >> 6, c8 = (t & 63) << 3;
  const float* src = w + (size_t)r * CDIM + c8;
  float4 v0 = *(const float4*)src, v1 = *(const float4*)(src + 4);
  float vv[8] = {v0.x, v0.y, v0.z, v0.w, v1.x, v1.y, v1.z, v1.w};
  u16x8 Hh, Ll;
#pragma unroll
  for (int i = 0; i < 8; i++) {
    u16 h = f2bf(vv[i]); Hh[i] = h; Ll[i] = f2bf(vv[i] - bf2f(h));
  }
  u16* dst = Bq + (size_t)r * CQKV;
  *(u16x8*)(dst + c8)        = Hh;
  *(u16x8*)(dst + 512 + c8)  = Hh;
  *(u16x8*)(dst + 1024 + c8) = Ll;
}

// ---- weight prep 2-term (v): qkv_w rows 1024.. -> [512][1024] bf16 = [Bh | Bh] ----
__global__ __launch_bounds__(256) void k_prep_bv(const float* __restrict__ w, u16* __restrict__ Bq) {
  int t = blockIdx.x * 256 + threadIdx.x;
  int r = t >> 6, c8 = (t & 63) << 3;
  const float* src = w + (size_t)(1024 + r) * CDIM + c8;
  float4 v0 = *(const float4*)src, v1 = *(const float4*)(src + 4);
  float vv[8] = {v0.x, v0.y, v0.z, v0.w, v1.x, v1.y, v1.z, v1.w};
  u16x8 Hh;
#pragma unroll
  for (int i = 0; i < 8; i++) Hh[i] = f2bf(vv[i]);
  u16* dst = Bq + (size_t)r * 1024;
  *(u16x8*)(dst + c8)       = Hh;
  *(u16x8*)(dst + 512 + c8) = Hh;
}

// ---- LePE weight transpose: lepe_w [512][9] f32 -> lwt [9][512] f32 ----
__global__ __launch_bounds__(256) void k_prep_lw(const float* __restrict__ lw, float* __restrict__ lwt) {
  int idx = blockIdx.x * 256 + threadIdx.x;   // 0..4607
  int tap = idx >> 9, ch = idx & 511;
  lwt[idx] = lw[ch * 9 + tap];
}

// ---- GEMM -> bf16 qkvh slab. A is [M][1024]=[Ah|Al], K-index wraps at 1024.
//      Optional: window-mean epilogue (qw/kw, routing) ; transposed V store (vTp). ----
__global__ __launch_bounds__(256) void k_gemm_h(const u16* __restrict__ A,
                                                const u16* __restrict__ B, int ldb, int K, int nbn,
                                                const float* __restrict__ bias,
                                                u16* __restrict__ qkvh, int coloff,
                                                float* __restrict__ qw, float* __restrict__ kw,
                                                u16* __restrict__ vTp) {
  __shared__ u16 As[128 * 32];
  __shared__ u16 Bs[128 * 32];
  int bx = blockIdx.x % nbn, by = blockIdx.x / nbn;
  int tid = threadIdx.x, lane = tid & 63, wid = tid >> 6;
  int wr = (wid >> 1) << 6, wc = (wid & 1) << 6;
  int l15 = lane & 15, h4 = lane >> 4;
  int ar0 = tid >> 2, ac0 = (tid & 3) << 3;
  const u16* Ab = A + (size_t)(by << 7) * 1024;
  const u16* Bb = B + (size_t)(bx << 7) * ldb;
  f32x4 acc[4][4] = {};
  for (int k0 = 0; k0 < K; k0 += 32) {
    int ka = (k0 < 1024) ? k0 : (k0 - 1024);
    gld16(Ab + (size_t)ar0 * 1024 + ka + ac0,        (char*)As + tid * 16);
    gld16(Ab + (size_t)(ar0 + 64) * 1024 + ka + ac0, (char*)As + 4096 + tid * 16);
    gld16(Bb + (size_t)ar0 * ldb + k0 + ac0,         (char*)Bs + tid * 16);
    gld16(Bb + (size_t)(ar0 + 64) * ldb + k0 + ac0,  (char*)Bs + 4096 + tid * 16);
    __syncthreads();
    s16x8 af[4], bfr[4];
#pragma unroll
    for (int f = 0; f < 4; f++) af[f]  = *(const s16x8*)((const char*)As + (wr + f * 16 + l15) * 64 + h4 * 16);
#pragma unroll
    for (int f = 0; f < 4; f++) bfr[f] = *(const s16x8*)((const char*)Bs + (wc + f * 16 + l15) * 64 + h4 * 16);
#pragma unroll
    for (int i = 0; i < 4; i++)
#pragma unroll
      for (int j = 0; j < 4; j++)
        acc[i][j] = __builtin_amdgcn_mfma_f32_16x16x32_bf16(af[i], bfr[j], acc[i][j], 0, 0, 0);
    __syncthreads();
  }
#pragma unroll
  for (int i = 0; i < 4; i++) {
#pragma unroll
    for (int j = 0; j < 4; j++) {
      int col = (bx << 7) + wc + j * 16 + l15;
      float bcol = bias[col];
      u16x4 pk;
#pragma unroll
      for (int rg = 0; rg < 4; rg++) {
        int row = (by << 7) + wr + i * 16 + (h4 << 2) + rg;
        u16 hv = f2bf(acc[i][j][rg] + bcol);
        qkvh[(size_t)row * CQKV + coloff + col] = hv;
        pk[rg] = hv;
      }
      if (vTp) {
        int row0 = (by << 7) + wr + i * 16 + (h4 << 2);
        *(u16x4*)(vTp + (size_t)col * NROWS + row0) = pk;
      }
    }
  }
  if (qw) {   // window means from f32 accumulators (routing precision)
    int np = (by << 1) + (wr >> 6);
#pragma unroll
    for (int j = 0; j < 4; j++) {
      float s = 0.f;
#pragma unroll
      for (int i = 0; i < 4; i++)
#pragma unroll
        for (int rg = 0; rg < 4; rg++) s += acc[i][j][rg];
      s += __shfl_xor(s, 16);
      s += __shfl_xor(s, 32);
      int col = (bx << 7) + wc + j * 16 + l15;
      if (h4 == 0) {
        float mv = s * (1.f / 64.f) + bias[col];
        if (col < 512) qw[(size_t)np * 512 + col] = mv;
        else           kw[(size_t)np * 512 + (col - 512)] = mv;
      }
    }
  }
}

// ---- GEMM2: C(f32, spatial layout) = A2([M][1024] wrap) @ B2^T + bias ----
__global__ __launch_bounds__(256) void k_gemm_out(const u16* __restrict__ A, const u16* __restrict__ B,
                                                  float* __restrict__ C, const float* __restrict__ bias) {
  __shared__ u16 As[128 * 32];
  __shared__ u16 Bs[128 * 32];
  const int K = CQKV, N = CDIM;
  int bx = blockIdx.x & 3, by = blockIdx.x >> 2;
  int tid = threadIdx.x, lane = tid & 63, wid = tid >> 6;
  int wr = (wid >> 1) << 6, wc = (wid & 1) << 6;
  int l15 = lane & 15, h4 = lane >> 4;
  int ar0 = tid >> 2, ac0 = (tid & 3) << 3;
  const u16* Ab = A + (size_t)(by << 7) * 1024;
  const u16* Bb = B + (size_t)(bx << 7) * K;
  f32x4 acc[4][4] = {};
  for (int k0 = 0; k0 < K; k0 += 32) {
    int ka = (k0 < 1024) ? k0 : (k0 - 1024);
    gld16(Ab + (size_t)ar0 * 1024 + ka + ac0,        (char*)As + tid * 16);
    gld16(Ab + (size_t)(ar0 + 64) * 1024 + ka + ac0, (char*)As + 4096 + tid * 16);
    gld16(Bb + (size_t)ar0 * K + k0 + ac0,           (char*)Bs + tid * 16);
    gld16(Bb + (size_t)(ar0 + 64) * K + k0 + ac0,    (char*)Bs + 4096 + tid * 16);
    __syncthreads();
    s16x8 af[4], bfr[4];
#pragma unroll
    for (int f = 0; f < 4; f++) af[f]  = *(const s16x8*)((const char*)As + (wr + f * 16 + l15) * 64 + h4 * 16);
#pragma unroll
    for (int f = 0; f < 4; f++) bfr[f] = *(const s16x8*)((const char*)Bs + (wc + f * 16 + l15) * 64 + h4 * 16);
#pragma unroll
    for (int i = 0; i < 4; i++)
#pragma unroll
      for (int j = 0; j < 4; j++)
        acc[i][j] = __builtin_amdgcn_mfma_f32_16x16x32_bf16(af[i], bfr[j], acc[i][j], 0, 0, 0);
    __syncthreads();
  }
#pragma unroll
  for (int i = 0; i < 4; i++) {
#pragma unroll
    for (int j = 0; j < 4; j++) {
      int col = (bx << 7) + wc + j * 16 + l15;
      float bcol = bias[col];
#pragma unroll
      for (int rg = 0; rg < 4; rg++) {
        int row = (by << 7) + wr + i * 16 + (h4 << 2) + rg;
        int n = row / (P2C * 64); int rem = row - n * (P2C * 64);
        int p = rem >> 6, pix = rem & 63;
        int y = (p / 7) * 8 + (pix >> 3), xx = (p % 7) * 8 + (pix & 7);
        C[(size_t)((n * HH + y) * WWI + xx) * N + col] = acc[i][j][rg] + bcol;
      }
    }
  }
}

// ---- routing: per (n,p) 49 logits from f32 window means, top-4 (stable ties) ----
__global__ __launch_bounds__(64) void k_route(const float* __restrict__ qw,
                                              const float* __restrict__ kw, int* __restrict__ ridx) {
  int np = blockIdx.x, n = np / P2C;
  int t = threadIdx.x;
  __shared__ float qrow[512];
  __shared__ float logit[64];
  for (int c = t; c < 512; c += 64) qrow[c] = qw[(size_t)np * 512 + c];
  __syncthreads();
  if (t < P2C) {
    const float* kr = kw + (size_t)(n * P2C + t) * 512;
    float s = 0.f;
    for (int c = 0; c < 512; c++) s += qrow[c] * kr[c];
    logit[t] = s;
  }
  __syncthreads();
  if (t == 0) {
    for (int tt = 0; tt < 4; tt++) {
      float best = -1e30f; int bi = 0;
      for (int q = 0; q < P2C; q++) if (logit[q] > best) { best = logit[q]; bi = q; }
      ridx[np * 4 + tt] = bi;
      logit[bi] = -1e30f;
    }
  }
}

// ---- LePE depthwise 3x3 (zero pad), transposed weights lwt[9][512] (coalesced) ----
__global__ __launch_bounds__(256) void k_lepe(const u16* __restrict__ qkvh,
                                              const float* __restrict__ lwt, const float* __restrict__ lb,
                                              u16* __restrict__ lepe) {
  int t = blockIdx.x * 256 + threadIdx.x;
  int r = t >> 6, c8 = (t & 63) << 3;
  int n = r / (P2C * 64); int rem = r - n * (P2C * 64);
  int p = rem >> 6, pix = rem & 63;
  int y = (p / 7) * 8 + (pix >> 3), xx = (p % 7) * 8 + (pix & 7);
  float acc[8];
  {
    float4 b0 = *(const float4*)(lb + c8), b1 = *(const float4*)(lb + c8 + 4);
    acc[0]=b0.x; acc[1]=b0.y; acc[2]=b0.z; acc[3]=b0.w;
    acc[4]=b1.x; acc[5]=b1.y; acc[6]=b1.z; acc[7]=b1.w;
  }
#pragma unroll
  for (int dy = -1; dy <= 1; dy++) {
#pragma unroll
    for (int dx = -1; dx <= 1; dx++) {
      int yy = y + dy, xz = xx + dx;
      if (yy < 0 || yy >= HH || xz < 0 || xz >= WWI) continue;
      int tap = (dy + 1) * 3 + (dx + 1);
      int p2 = (yy >> 3) * 7 + (xz >> 3), px2 = (yy & 7) * 8 + (xz & 7);
      const u16* v = qkvh + ((size_t)((n * P2C + p2) * 64 + px2)) * CQKV + 1024 + c8;
      u16x8 a = *(const u16x8*)v;
      const float* wrow = lwt + tap * 512 + c8;
      float4 w0 = *(const float4*)wrow, w1 = *(const float4*)(wrow + 4);
      float ww[8] = {w0.x, w0.y, w0.z, w0.w, w1.x, w1.y, w1.z, w1.w};
#pragma unroll
      for (int i = 0; i < 8; i++) acc[i] += bf2f(a[i]) * ww[i];
    }
  }
  u16x8 o;
#pragma unroll
  for (int i = 0; i < 8; i++) o[i] = f2bf(acc[i]);
  *(u16x8*)(lepe + (size_t)r * CDIM + c8) = o;
}

// ---- attention: block=(np, head-quad), wave=head. Swapped S^T=K*Q^T.
//      K frags hoisted (fq-independent); V from vT via 8B vector loads;
//      softmax: raw-max + exp2(fma); P->bf16 via v_cvt_pk_bf16_f32.
//      Epilogue: + lepe, write A2 [hi|lo] (1024 wide). ----
__global__ __launch_bounds__(256) void k_attn(const u16* __restrict__ qkvh,
                                              const u16* __restrict__ vT,
                                              const int* __restrict__ ridx,
                                              const u16* __restrict__ lepe, u16* __restrict__ A2) {
  int b = blockIdx.x;
  int mq = b & 3, np = b >> 2;
  int n = np / P2C;
  int wid = threadIdx.x >> 6, lane = threadIdx.x & 63;
  int m = (mq << 2) + wid;
  int l15 = lane & 15, h4 = lane >> 4;
  int krow[4];
#pragma unroll
  for (int w = 0; w < 4; w++) krow[w] = (n * P2C + ridx[np * 4 + w]) * 64;
  size_t qrow0 = (size_t)np * 64;
  union FR  { s16x8 s; u16 u[8]; };
  union FRu { s16x8 s; unsigned w[4]; };
  f32x4 zero = {0.f, 0.f, 0.f, 0.f};
  // hoisted K fragments (fq-independent)
  FR kf[16];
#pragma unroll
  for (int fk = 0; fk < 16; fk++) {
    int key = fk * 16 + l15;
    kf[fk].s = *(const s16x8*)(qkvh + (size_t)(krow[key >> 6] + (key & 63)) * CQKV + 512 + m * 32 + h4 * 8);
  }
#pragma unroll
  for (int fq = 0; fq < 4; fq++) {
    s16x8 qf = *(const s16x8*)(qkvh + (qrow0 + fq * 16 + l15) * CQKV + m * 32 + h4 * 8);
    f32x4 st[16];
#pragma unroll
    for (int fk = 0; fk < 16; fk++)
      st[fk] = __builtin_amdgcn_mfma_f32_16x16x32_bf16(kf[fk].s, qf, zero, 0, 0, 0);
    float mx = -1e30f;
#pragma unroll
    for (int fk = 0; fk < 16; fk++)
#pragma unroll
      for (int rg = 0; rg < 4; rg++) mx = fmaxf(mx, st[fk][rg]);
    mx = fmaxf(mx, __shfl_xor(mx, 16));
    mx = fmaxf(mx, __shfl_xor(mx, 32));
    float nmc = -mx * SC_LOG2E;
    float sum = 0.f;
#pragma unroll
    for (int fk = 0; fk < 16; fk++)
#pragma unroll
      for (int rg = 0; rg < 4; rg++) {
        float e = exp2f(fmaf(st[fk][rg], SC_LOG2E, nmc));
        st[fk][rg] = e; sum += e;
      }
    sum += __shfl_xor(sum, 16);
    sum += __shfl_xor(sum, 32);
    f32x4 oacc[2] = {zero, zero};
#pragma unroll
    for (int s8 = 0; s8 < 8; s8++) {
      FRu pa;
      pa.w[0] = cvtpk(st[2 * s8][0],     st[2 * s8][1]);
      pa.w[1] = cvtpk(st[2 * s8][2],     st[2 * s8][3]);
      pa.w[2] = cvtpk(st[2 * s8 + 1][0], st[2 * s8 + 1][1]);
      pa.w[3] = cvtpk(st[2 * s8 + 1][2], st[2 * s8 + 1][3]);
      int grow_lo = krow[s8 >> 1] + ((s8 & 1) << 5) + (h4 << 2);
#pragma unroll
      for (int fd = 0; fd < 2; fd++) {
        int col = m * 32 + fd * 16 + l15;
        const u16* vb = vT + (size_t)col * NROWS;
        FR vf;
        *(u16x4*)&vf.u[0] = *(const u16x4*)(vb + grow_lo);
        *(u16x4*)&vf.u[4] = *(const u16x4*)(vb + grow_lo + 16);
        oacc[fd] = __builtin_amdgcn_mfma_f32_16x16x32_bf16(pa.s, vf.s, oacc[fd], 0, 0, 0);
      }
    }
#pragma unroll
    for (int rg = 0; rg < 4; rg++) {
      float sq = __shfl(sum, (h4 << 2) + rg);
      int q = fq * 16 + (h4 << 2) + rg;
#pragma unroll
      for (int fd = 0; fd < 2; fd++) {
        int col = m * 32 + fd * 16 + l15;
        size_t row = qrow0 + q;
        float val = oacc[fd][rg] / sq + bf2f(lepe[row * CDIM + col]);
        u16 hi = f2bf(val);
        u16 lo = f2bf(val - bf2f(hi));
        A2[row * 1024 + col]       = hi;
        A2[row * 1024 + 512 + col] = lo;
      }
    }
  }
}

extern "C" void kernel_launch(void* const* d_in, const int* in_sizes, int n_in,
                              void* d_out, int out_size, void* d_ws, size_t ws_size,
                              hipStream_t stream) {
  (void)in_sizes; (void)n_in; (void)out_size; (void)ws_size;
  const float* x      = (const float*)d_in[0];
  const float* qkv_w  = (const float*)d_in[1];
  const float* qkv_b  = (const float*)d_in[2];
  const float* wo_w   = (const float*)d_in[3];
  const float* wo_b   = (const float*)d_in[4];
  const float* lepe_w = (const float*)d_in[5];
  const float* lepe_b = (const float*)d_in[6];
  float* out = (float*)d_out;
  char* ws = (char*)d_ws;
  size_t off = 0;
  auto alc = [&](size_t b) { char* p = ws + off; off += (b + 255) & ~(size_t)255; return p; };
  u16*   B1    = (u16*)  alc((size_t)1024 * CQKV * 2);        //  3.1 MB  (q,k rows, 3-term)
  u16*   Bv    = (u16*)  alc((size_t)512 * 1024 * 2);         //  1.0 MB  (v rows, 2-term)
  u16*   B2    = (u16*)  alc((size_t)CDIM * CQKV * 2);        //  1.6 MB
  float* lwt   = (float*)alc((size_t)9 * 512 * 4);            //  18 KB
  u16*   qkvh  = (u16*)  alc((size_t)NROWS * CQKV * 2);       // 77.1 MB
  u16*   vT    = (u16*)  alc((size_t)CDIM * NROWS * 2);       // 25.7 MB (v transposed)
  float* qw    = (float*)alc((size_t)NB * P2C * CDIM * 4);    //  0.8 MB
  float* kw    = (float*)alc((size_t)NB * P2C * CDIM * 4);    //  0.8 MB
  int*   ridx  = (int*)  alc((size_t)NB * P2C * 4 * 4);       //  6 KB
  u16*   lepe  = (u16*)  alc((size_t)NROWS * CDIM * 2);       // 25.7 MB
  u16*   A12   = (u16*)  alc((size_t)NROWS * 1024 * 2);       // 51.4 MB (A1, later A2)
  // total ~187 MB

  k_prep_a1<<<dim3(6272), dim3(256), 0, stream>>>(x, A12);
  k_prep_b <<<dim3(256),  dim3(256), 0, stream>>>(qkv_w, B1);     // rows 0..1023 (q,k)
  k_prep_bv<<<dim3(128),  dim3(256), 0, stream>>>(qkv_w, Bv);     // rows 1024..1535 (v)
  k_prep_b <<<dim3(128),  dim3(256), 0, stream>>>(wo_w, B2);
  k_prep_lw<<<dim3(18),   dim3(256), 0, stream>>>(lepe_w, lwt);
  k_gemm_h <<<dim3(1568), dim3(256), 0, stream>>>(A12, B1, CQKV, CQKV, 8,
                                                  qkv_b, qkvh, 0, qw, kw, nullptr);
  k_gemm_h <<<dim3(784),  dim3(256), 0, stream>>>(A12, Bv, 1024, 1024, 4,
                                                  qkv_b + 1024, qkvh, 1024, nullptr, nullptr, vT);
  k_route <<<dim3(392),  dim3(64),  0, stream>>>(qw, kw, ridx);
  k_lepe  <<<dim3(6272), dim3(256), 0, stream>>>(qkvh, lwt, lepe_b, lepe);
  k_attn  <<<dim3(1568), dim3(256), 0, stream>>>(qkvh, vT, ridx, lepe, A12);
  k_gemm_out<<<dim3(784), dim3(256), 0, stream>>>(A12, B2, out, wo_b);
}

// Round 6
// 500.023 us; speedup vs baseline: 1.4608x; 1.0259x over previous
//
#include <hip/hip_runtime.h>

typedef unsigned short u16;
typedef __attribute__((ext_vector_type(8))) short  s16x8;
typedef __attribute__((ext_vector_type(8))) u16    u16x8;
typedef __attribute__((ext_vector_type(4))) u16    u16x4;
typedef __attribute__((ext_vector_type(4))) float  f32x4;

#define NB    8
#define HH    56
#define WWI   56
#define CDIM  512
#define CQKV  1536
#define P2C   49
#define NROWS (NB*P2C*64)      // 25088 windowed pixel rows
// SCALE * log2(e)
#define SC_LOG2E 0.06375871682f

__device__ __forceinline__ u16 f2bf(float f) {
  union { float f; unsigned u; } x; x.f = f;
  unsigned r = x.u + 0x7fffu + ((x.u >> 16) & 1u);
  return (u16)(r >> 16);
}
__device__ __forceinline__ float bf2f(u16 h) {
  union { unsigned u; float f; } x; x.u = ((unsigned)h) << 16;
  return x.f;
}
__device__ __forceinline__ unsigned cvtpk(float lo, float hi) {
  unsigned d;
  asm("v_cvt_pk_bf16_f32 %0, %1, %2" : "=v"(d) : "v"(lo), "v"(hi));
  return d;
}

__device__ __forceinline__ void gld16(const void* g, void* l) {
  __builtin_amdgcn_global_load_lds((const __attribute__((address_space(1))) void*)g,
                                   (__attribute__((address_space(3))) void*)l, 16, 0, 0);
}

// ---- A1 prep: x (NHWC f32) -> windowed [25088][1024] bf16 = [Ah | Al] ----
__global__ __launch_bounds__(256) void k_prep_a1(const float* __restrict__ x, u16* __restrict__ A1) {
  int t = blockIdx.x * 256 + threadIdx.x;
  int r = t >> 6, c8 = (t & 63) << 3;
  int n = r / (P2C * 64); int rem = r - n * (P2C * 64);
  int p = rem >> 6, pix = rem & 63;
  int y = (p / 7) * 8 + (pix >> 3), xx = (p % 7) * 8 + (pix & 7);
  const float* src = x + ((size_t)((n * HH + y) * WWI + xx)) * CDIM + c8;
  float4 v0 = *(const float4*)src, v1 = *(const float4*)(src + 4);
  float vv[8] = {v0.x, v0.y, v0.z, v0.w, v1.x, v1.y, v1.z, v1.w};
  u16x8 Hh, Ll;
#pragma unroll
  for (int i = 0; i < 8; i++) {
    u16 h = f2bf(vv[i]); Hh[i] = h; Ll[i] = f2bf(vv[i] - bf2f(h));
  }
  u16* dst = A1 + (size_t)r * 1024;
  *(u16x8*)(dst + c8)       = Hh;
  *(u16x8*)(dst + 512 + c8) = Ll;
}

// ---- weight prep 3-term: [rows][512] f32 -> [rows][1536] bf16 = [Bh | Bh | Bl] ----
__global__ __launch_bounds__(256) void k_prep_b(const float* __restrict__ w, u16* __restrict__ Bq) {
  int t = blockIdx.x * 256 + threadIdx.x;
  int r = t >> 6, c8 = (t & 63) << 3;
  const float* src = w + (size_t)r * CDIM + c8;
  float4 v0 = *(const float4*)src, v1 = *(const float4*)(src + 4);
  float vv[8] = {v0.x, v0.y, v0.z, v0.w, v1.x, v1.y, v1.z, v1.w};
  u16x8 Hh, Ll;
#pragma unroll
  for (int i = 0; i < 8; i++) {
    u16 h = f2bf(vv[i]); Hh[i] = h; Ll[i] = f2bf(vv[i] - bf2f(h));
  }
  u16* dst = Bq + (size_t)r * CQKV;
  *(u16x8*)(dst + c8)        = Hh;
  *(u16x8*)(dst + 512 + c8)  = Hh;
  *(u16x8*)(dst + 1024 + c8) = Ll;
}

// ---- weight prep 2-term (v): qkv_w rows 1024.. -> [512][1024] bf16 = [Bh | Bh] ----
__global__ __launch_bounds__(256) void k_prep_bv(const float* __restrict__ w, u16* __restrict__ Bq) {
  int t = blockIdx.x * 256 + threadIdx.x;
  int r = t >> 6, c8 = (t & 63) << 3;
  const float* src = w + (size_t)(1024 + r) * CDIM + c8;
  float4 v0 = *(const float4*)src, v1 = *(const float4*)(src + 4);
  float vv[8] = {v0.x, v0.y, v0.z, v0.w, v1.x, v1.y, v1.z, v1.w};
  u16x8 Hh;
#pragma unroll
  for (int i = 0; i < 8; i++) Hh[i] = f2bf(vv[i]);
  u16* dst = Bq + (size_t)r * 1024;
  *(u16x8*)(dst + c8)       = Hh;
  *(u16x8*)(dst + 512 + c8) = Hh;
}

// ---- LePE weight transpose: lepe_w [512][9] f32 -> lwt [9][512] f32 ----
__global__ __launch_bounds__(256) void k_prep_lw(const float* __restrict__ lw, float* __restrict__ lwt) {
  int idx = blockIdx.x * 256 + threadIdx.x;   // 0..4607
  int tap = idx >> 9, ch = idx & 511;
  lwt[idx] = lw[ch * 9 + tap];
}

// ---- GEMM -> bf16 qkvh slab. A is [M][1024]=[Ah|Al], K-index wraps at 1024.
//      Optional: window-mean epilogue (qw/kw, routing) ; transposed V store (vTp). ----
__global__ __launch_bounds__(256) void k_gemm_h(const u16* __restrict__ A,
                                                const u16* __restrict__ B, int ldb, int K, int nbn,
                                                const float* __restrict__ bias,
                                                u16* __restrict__ qkvh, int coloff,
                                                float* __restrict__ qw, float* __restrict__ kw,
                                                u16* __restrict__ vTp) {
  __shared__ u16 As[128 * 32];
  __shared__ u16 Bs[128 * 32];
  int bx = blockIdx.x % nbn, by = blockIdx.x / nbn;
  int tid = threadIdx.x, lane = tid & 63, wid = tid >> 6;
  int wr = (wid >> 1) << 6, wc = (wid & 1) << 6;
  int l15 = lane & 15, h4 = lane >> 4;
  int ar0 = tid >> 2, ac0 = (tid & 3) << 3;
  const u16* Ab = A + (size_t)(by << 7) * 1024;
  const u16* Bb = B + (size_t)(bx << 7) * ldb;
  f32x4 acc[4][4] = {};
  for (int k0 = 0; k0 < K; k0 += 32) {
    int ka = (k0 < 1024) ? k0 : (k0 - 1024);
    gld16(Ab + (size_t)ar0 * 1024 + ka + ac0,        (char*)As + tid * 16);
    gld16(Ab + (size_t)(ar0 + 64) * 1024 + ka + ac0, (char*)As + 4096 + tid * 16);
    gld16(Bb + (size_t)ar0 * ldb + k0 + ac0,         (char*)Bs + tid * 16);
    gld16(Bb + (size_t)(ar0 + 64) * ldb + k0 + ac0,  (char*)Bs + 4096 + tid * 16);
    __syncthreads();
    s16x8 af[4], bfr[4];
#pragma unroll
    for (int f = 0; f < 4; f++) af[f]  = *(const s16x8*)((const char*)As + (wr + f * 16 + l15) * 64 + h4 * 16);
#pragma unroll
    for (int f = 0; f < 4; f++) bfr[f] = *(const s16x8*)((const char*)Bs + (wc + f * 16 + l15) * 64 + h4 * 16);
#pragma unroll
    for (int i = 0; i < 4; i++)
#pragma unroll
      for (int j = 0; j < 4; j++)
        acc[i][j] = __builtin_amdgcn_mfma_f32_16x16x32_bf16(af[i], bfr[j], acc[i][j], 0, 0, 0);
    __syncthreads();
  }
#pragma unroll
  for (int i = 0; i < 4; i++) {
#pragma unroll
    for (int j = 0; j < 4; j++) {
      int col = (bx << 7) + wc + j * 16 + l15;
      float bcol = bias[col];
      u16x4 pk;
#pragma unroll
      for (int rg = 0; rg < 4; rg++) {
        int row = (by << 7) + wr + i * 16 + (h4 << 2) + rg;
        u16 hv = f2bf(acc[i][j][rg] + bcol);
        qkvh[(size_t)row * CQKV + coloff + col] = hv;
        pk[rg] = hv;
      }
      if (vTp) {
        int row0 = (by << 7) + wr + i * 16 + (h4 << 2);
        *(u16x4*)(vTp + (size_t)col * NROWS + row0) = pk;
      }
    }
  }
  if (qw) {   // window means from f32 accumulators (routing precision)
    int np = (by << 1) + (wr >> 6);
#pragma unroll
    for (int j = 0; j < 4; j++) {
      float s = 0.f;
#pragma unroll
      for (int i = 0; i < 4; i++)
#pragma unroll
        for (int rg = 0; rg < 4; rg++) s += acc[i][j][rg];
      s += __shfl_xor(s, 16);
      s += __shfl_xor(s, 32);
      int col = (bx << 7) + wc + j * 16 + l15;
      if (h4 == 0) {
        float mv = s * (1.f / 64.f) + bias[col];
        if (col < 512) qw[(size_t)np * 512 + col] = mv;
        else           kw[(size_t)np * 512 + (col - 512)] = mv;
      }
    }
  }
}

// ---- GEMM2: C(f32, spatial layout) = A2([M][1024] wrap) @ B2^T + bias ----
__global__ __launch_bounds__(256) void k_gemm_out(const u16* __restrict__ A, const u16* __restrict__ B,
                                                  float* __restrict__ C, const float* __restrict__ bias) {
  __shared__ u16 As[128 * 32];
  __shared__ u16 Bs[128 * 32];
  const int K = CQKV, N = CDIM;
  int bx = blockIdx.x & 3, by = blockIdx.x >> 2;
  int tid = threadIdx.x, lane = tid & 63, wid = tid >> 6;
  int wr = (wid >> 1) << 6, wc = (wid & 1) << 6;
  int l15 = lane & 15, h4 = lane >> 4;
  int ar0 = tid >> 2, ac0 = (tid & 3) << 3;
  const u16* Ab = A + (size_t)(by << 7) * 1024;
  const u16* Bb = B + (size_t)(bx << 7) * K;
  f32x4 acc[4][4] = {};
  for (int k0 = 0; k0 < K; k0 += 32) {
    int ka = (k0 < 1024) ? k0 : (k0 - 1024);
    gld16(Ab + (size_t)ar0 * 1024 + ka + ac0,        (char*)As + tid * 16);
    gld16(Ab + (size_t)(ar0 + 64) * 1024 + ka + ac0, (char*)As + 4096 + tid * 16);
    gld16(Bb + (size_t)ar0 * K + k0 + ac0,           (char*)Bs + tid * 16);
    gld16(Bb + (size_t)(ar0 + 64) * K + k0 + ac0,    (char*)Bs + 4096 + tid * 16);
    __syncthreads();
    s16x8 af[4], bfr[4];
#pragma unroll
    for (int f = 0; f < 4; f++) af[f]  = *(const s16x8*)((const char*)As + (wr + f * 16 + l15) * 64 + h4 * 16);
#pragma unroll
    for (int f = 0; f < 4; f++) bfr[f] = *(const s16x8*)((const char*)Bs + (wc + f * 16 + l15) * 64 + h4 * 16);
#pragma unroll
    for (int i = 0; i < 4; i++)
#pragma unroll
      for (int j = 0; j < 4; j++)
        acc[i][j] = __builtin_amdgcn_mfma_f32_16x16x32_bf16(af[i], bfr[j], acc[i][j], 0, 0, 0);
    __syncthreads();
  }
#pragma unroll
  for (int i = 0; i < 4; i++) {
#pragma unroll
    for (int j = 0; j < 4; j++) {
      int col = (bx << 7) + wc + j * 16 + l15;
      float bcol = bias[col];
#pragma unroll
      for (int rg = 0; rg < 4; rg++) {
        int row = (by << 7) + wr + i * 16 + (h4 << 2) + rg;
        int n = row / (P2C * 64); int rem = row - n * (P2C * 64);
        int p = rem >> 6, pix = rem & 63;
        int y = (p / 7) * 8 + (pix >> 3), xx = (p % 7) * 8 + (pix & 7);
        C[(size_t)((n * HH + y) * WWI + xx) * N + col] = acc[i][j][rg] + bcol;
      }
    }
  }
}

// ---- routing: per (n,p) 49 logits from f32 window means, top-4 (stable ties) ----
__global__ __launch_bounds__(64) void k_route(const float* __restrict__ qw,
                                              const float* __restrict__ kw, int* __restrict__ ridx) {
  int np = blockIdx.x, n = np / P2C;
  int t = threadIdx.x;
  __shared__ float qrow[512];
  __shared__ float logit[64];
  for (int c = t; c < 512; c += 64) qrow[c] = qw[(size_t)np * 512 + c];
  __syncthreads();
  if (t < P2C) {
    const float* kr = kw + (size_t)(n * P2C + t) * 512;
    float s = 0.f;
    for (int c = 0; c < 512; c++) s += qrow[c] * kr[c];
    logit[t] = s;
  }
  __syncthreads();
  if (t == 0) {
    for (int tt = 0; tt < 4; tt++) {
      float best = -1e30f; int bi = 0;
      for (int q = 0; q < P2C; q++) if (logit[q] > best) { best = logit[q]; bi = q; }
      ridx[np * 4 + tt] = bi;
      logit[bi] = -1e30f;
    }
  }
}

// ---- LePE depthwise 3x3 (zero pad), transposed weights lwt[9][512] (coalesced) ----
__global__ __launch_bounds__(256) void k_lepe(const u16* __restrict__ qkvh,
                                              const float* __restrict__ lwt, const float* __restrict__ lb,
                                              u16* __restrict__ lepe) {
  int t = blockIdx.x * 256 + threadIdx.x;
  int r = t >> 6, c8 = (t & 63) << 3;
  int n = r / (P2C * 64); int rem = r - n * (P2C * 64);
  int p = rem >> 6, pix = rem & 63;
  int y = (p / 7) * 8 + (pix >> 3), xx = (p % 7) * 8 + (pix & 7);
  float acc[8];
  {
    float4 b0 = *(const float4*)(lb + c8), b1 = *(const float4*)(lb + c8 + 4);
    acc[0]=b0.x; acc[1]=b0.y; acc[2]=b0.z; acc[3]=b0.w;
    acc[4]=b1.x; acc[5]=b1.y; acc[6]=b1.z; acc[7]=b1.w;
  }
#pragma unroll
  for (int dy = -1; dy <= 1; dy++) {
#pragma unroll
    for (int dx = -1; dx <= 1; dx++) {
      int yy = y + dy, xz = xx + dx;
      if (yy < 0 || yy >= HH || xz < 0 || xz >= WWI) continue;
      int tap = (dy + 1) * 3 + (dx + 1);
      int p2 = (yy >> 3) * 7 + (xz >> 3), px2 = (yy & 7) * 8 + (xz & 7);
      const u16* v = qkvh + ((size_t)((n * P2C + p2) * 64 + px2)) * CQKV + 1024 + c8;
      u16x8 a = *(const u16x8*)v;
      const float* wrow = lwt + tap * 512 + c8;
      float4 w0 = *(const float4*)wrow, w1 = *(const float4*)(wrow + 4);
      float ww[8] = {w0.x, w0.y, w0.z, w0.w, w1.x, w1.y, w1.z, w1.w};
#pragma unroll
      for (int i = 0; i < 8; i++) acc[i] += bf2f(a[i]) * ww[i];
    }
  }
  u16x8 o;
#pragma unroll
  for (int i = 0; i < 8; i++) o[i] = f2bf(acc[i]);
  *(u16x8*)(lepe + (size_t)r * CDIM + c8) = o;
}

// ---- attention: block=(np, head-quad), wave=head. Swapped S^T=K*Q^T.
//      K frags hoisted (global, fq-independent). V staged in LDS (64KB) from vT:
//      512 strips of 128B ([colL][w][64 keys]), 16B-chunk XOR swizzle (src-side),
//      per-lane V frags = 2x 8B ds_read. softmax exp2(fma); P->bf16 cvt_pk.
//      Epilogue: + lepe, write A2 [hi|lo] (1024 wide). ----
__global__ __launch_bounds__(256) void k_attn(const u16* __restrict__ qkvh,
                                              const u16* __restrict__ vT,
                                              const int* __restrict__ ridx,
                                              const u16* __restrict__ lepe, u16* __restrict__ A2) {
  __shared__ u16 Vs[32768];    // 64 KB
  int b = blockIdx.x;
  int mq = b & 3, np = b >> 2;
  int n = np / P2C;
  int tid = threadIdx.x;
  int wid = tid >> 6, lane = tid & 63;
  int m = (mq << 2) + wid;
  int l15 = lane & 15, h4 = lane >> 4;
  int krow[4];
#pragma unroll
  for (int w = 0; w < 4; w++) krow[w] = (n * P2C + ridx[np * 4 + w]) * 64;
  size_t qrow0 = (size_t)np * 64;
  union FR  { s16x8 s; u16 u[8]; };
  union FRu { s16x8 s; unsigned w[4]; };
  f32x4 zero = {0.f, 0.f, 0.f, 0.f};
  // ---- stage V into LDS: chunk ch (16B) -> strip=ch>>3 (colL=strip>>2, w=strip&3),
  //      dest chunk c16d=ch&7 holds source chunk c16d ^ (colL&7)
  int colbase = mq << 7;
#pragma unroll
  for (int i = 0; i < 16; i++) {
    int ch = i * 256 + tid;
    int strip = ch >> 3, c16d = ch & 7;
    int colL = strip >> 2, w = strip & 3;
    int c16s = c16d ^ (colL & 7);
    gld16(vT + (size_t)(colbase + colL) * NROWS + krow[w] + c16s * 8, (char*)Vs + ch * 16);
  }
  // hoisted K fragments (fq-independent)
  FR kf[16];
#pragma unroll
  for (int fk = 0; fk < 16; fk++) {
    int key = fk * 16 + l15;
    kf[fk].s = *(const s16x8*)(qkvh + (size_t)(krow[key >> 6] + (key & 63)) * CQKV + 512 + m * 32 + h4 * 8);
  }
  __syncthreads();
#pragma unroll
  for (int fq = 0; fq < 4; fq++) {
    s16x8 qf = *(const s16x8*)(qkvh + (qrow0 + fq * 16 + l15) * CQKV + m * 32 + h4 * 8);
    f32x4 st[16];
#pragma unroll
    for (int fk = 0; fk < 16; fk++)
      st[fk] = __builtin_amdgcn_mfma_f32_16x16x32_bf16(kf[fk].s, qf, zero, 0, 0, 0);
    float mx = -1e30f;
#pragma unroll
    for (int fk = 0; fk < 16; fk++)
#pragma unroll
      for (int rg = 0; rg < 4; rg++) mx = fmaxf(mx, st[fk][rg]);
    mx = fmaxf(mx, __shfl_xor(mx, 16));
    mx = fmaxf(mx, __shfl_xor(mx, 32));
    float nmc = -mx * SC_LOG2E;
    float sum = 0.f;
#pragma unroll
    for (int fk = 0; fk < 16; fk++)
#pragma unroll
      for (int rg = 0; rg < 4; rg++) {
        float e = exp2f(fmaf(st[fk][rg], SC_LOG2E, nmc));
        st[fk][rg] = e; sum += e;
      }
    sum += __shfl_xor(sum, 16);
    sum += __shfl_xor(sum, 32);
    f32x4 oacc[2] = {zero, zero};
#pragma unroll
    for (int s8 = 0; s8 < 8; s8++) {
      FRu pa;
      pa.w[0] = cvtpk(st[2 * s8][0],     st[2 * s8][1]);
      pa.w[1] = cvtpk(st[2 * s8][2],     st[2 * s8][3]);
      pa.w[2] = cvtpk(st[2 * s8 + 1][0], st[2 * s8 + 1][1]);
      pa.w[3] = cvtpk(st[2 * s8 + 1][2], st[2 * s8 + 1][3]);
      int wv = s8 >> 1;
      int c16 = ((s8 & 1) << 2) + (h4 >> 1);
      int lo8 = (h4 & 1) << 3;
#pragma unroll
      for (int fd = 0; fd < 2; fd++) {
        int colL = (wid << 5) + (fd << 4) + l15;
        int strip = (colL << 2) + wv;
        int swz = colL & 7;
        const char* base = (const char*)Vs + strip * 128 + lo8;
        FR vf;
        *(u16x4*)&vf.u[0] = *(const u16x4*)(base + ((c16 ^ swz) << 4));
        *(u16x4*)&vf.u[4] = *(const u16x4*)(base + (((c16 + 2) ^ swz) << 4));
        oacc[fd] = __builtin_amdgcn_mfma_f32_16x16x32_bf16(pa.s, vf.s, oacc[fd], 0, 0, 0);
      }
    }
#pragma unroll
    for (int rg = 0; rg < 4; rg++) {
      float sq = __shfl(sum, (h4 << 2) + rg);
      int q = fq * 16 + (h4 << 2) + rg;
#pragma unroll
      for (int fd = 0; fd < 2; fd++) {
        int col = m * 32 + fd * 16 + l15;
        size_t row = qrow0 + q;
        float val = oacc[fd][rg] / sq + bf2f(lepe[row * CDIM + col]);
        u16 hi = f2bf(val);
        u16 lo = f2bf(val - bf2f(hi));
        A2[row * 1024 + col]       = hi;
        A2[row * 1024 + 512 + col] = lo;
      }
    }
  }
}

extern "C" void kernel_launch(void* const* d_in, const int* in_sizes, int n_in,
                              void* d_out, int out_size, void* d_ws, size_t ws_size,
                              hipStream_t stream) {
  (void)in_sizes; (void)n_in; (void)out_size; (void)ws_size;
  const float* x      = (const float*)d_in[0];
  const float* qkv_w  = (const float*)d_in[1];
  const float* qkv_b  = (const float*)d_in[2];
  const float* wo_w   = (const float*)d_in[3];
  const float* wo_b   = (const float*)d_in[4];
  const float* lepe_w = (const float*)d_in[5];
  const float* lepe_b = (const float*)d_in[6];
  float* out = (float*)d_out;
  char* ws = (char*)d_ws;
  size_t off = 0;
  auto alc = [&](size_t b) { char* p = ws + off; off += (b + 255) & ~(size_t)255; return p; };
  u16*   B1    = (u16*)  alc((size_t)1024 * CQKV * 2);        //  3.1 MB  (q,k rows, 3-term)
  u16*   Bv    = (u16*)  alc((size_t)512 * 1024 * 2);         //  1.0 MB  (v rows, 2-term)
  u16*   B2    = (u16*)  alc((size_t)CDIM * CQKV * 2);        //  1.6 MB
  float* lwt   = (float*)alc((size_t)9 * 512 * 4);            //  18 KB
  u16*   qkvh  = (u16*)  alc((size_t)NROWS * CQKV * 2);       // 77.1 MB
  u16*   vT    = (u16*)  alc((size_t)CDIM * NROWS * 2);       // 25.7 MB (v transposed)
  float* qw    = (float*)alc((size_t)NB * P2C * CDIM * 4);    //  0.8 MB
  float* kw    = (float*)alc((size_t)NB * P2C * CDIM * 4);    //  0.8 MB
  int*   ridx  = (int*)  alc((size_t)NB * P2C * 4 * 4);       //  6 KB
  u16*   lepe  = (u16*)  alc((size_t)NROWS * CDIM * 2);       // 25.7 MB
  u16*   A12   = (u16*)  alc((size_t)NROWS * 1024 * 2);       // 51.4 MB (A1, later A2)
  // total ~187 MB

  k_prep_a1<<<dim3(6272), dim3(256), 0, stream>>>(x, A12);
  k_prep_b <<<dim3(256),  dim3(256), 0, stream>>>(qkv_w, B1);     // rows 0..1023 (q,k)
  k_prep_bv<<<dim3(128),  dim3(256), 0, stream>>>(qkv_w, Bv);     // rows 1024..1535 (v)
  k_prep_b <<<dim3(128),  dim3(256), 0, stream>>>(wo_w, B2);
  k_prep_lw<<<dim3(18),   dim3(256), 0, stream>>>(lepe_w, lwt);
  k_gemm_h <<<dim3(1568), dim3(256), 0, stream>>>(A12, B1, CQKV, CQKV, 8,
                                                  qkv_b, qkvh, 0, qw, kw, nullptr);
  k_gemm_h <<<dim3(784),  dim3(256), 0, stream>>>(A12, Bv, 1024, 1024, 4,
                                                  qkv_b + 1024, qkvh, 1024, nullptr, nullptr, vT);
  k_route <<<dim3(392),  dim3(64),  0, stream>>>(qw, kw, ridx);
  k_lepe  <<<dim3(6272), dim3(256), 0, stream>>>(qkvh, lwt, lepe_b, lepe);
  k_attn  <<<dim3(1568), dim3(256), 0, stream>>>(qkvh, vT, ridx, lepe, A12);
  k_gemm_out<<<dim3(784), dim3(256), 0, stream>>>(A12, B2, out, wo_b);
}

// Round 7
// 482.629 us; speedup vs baseline: 1.5134x; 1.0360x over previous
//
#include <hip/hip_runtime.h>

typedef unsigned short u16;
typedef __attribute__((ext_vector_type(8))) short  s16x8;
typedef __attribute__((ext_vector_type(8))) u16    u16x8;
typedef __attribute__((ext_vector_type(4))) u16    u16x4;
typedef __attribute__((ext_vector_type(4))) float  f32x4;

#define NB    8
#define HH    56
#define WWI   56
#define CDIM  512
#define CQKV  1536
#define P2C   49
#define NROWS (NB*P2C*64)      // 25088 windowed pixel rows
// SCALE * log2(e)
#define SC_LOG2E 0.06375871682f

__device__ __forceinline__ u16 f2bf(float f) {
  union { float f; unsigned u; } x; x.f = f;
  unsigned r = x.u + 0x7fffu + ((x.u >> 16) & 1u);
  return (u16)(r >> 16);
}
__device__ __forceinline__ float bf2f(u16 h) {
  union { unsigned u; float f; } x; x.u = ((unsigned)h) << 16;
  return x.f;
}
__device__ __forceinline__ unsigned cvtpk(float lo, float hi) {
  unsigned d;
  asm("v_cvt_pk_bf16_f32 %0, %1, %2" : "=v"(d) : "v"(lo), "v"(hi));
  return d;
}

__device__ __forceinline__ void gld16(const void* g, void* l) {
  __builtin_amdgcn_global_load_lds((const __attribute__((address_space(1))) void*)g,
                                   (__attribute__((address_space(3))) void*)l, 16, 0, 0);
}

// ---- A1 prep: x (NHWC f32) -> windowed [25088][1024] bf16 = [Ah | Al] ----
__global__ __launch_bounds__(256) void k_prep_a1(const float* __restrict__ x, u16* __restrict__ A1) {
  int t = blockIdx.x * 256 + threadIdx.x;
  int r = t >> 6, c8 = (t & 63) << 3;
  int n = r / (P2C * 64); int rem = r - n * (P2C * 64);
  int p = rem >> 6, pix = rem & 63;
  int y = (p / 7) * 8 + (pix >> 3), xx = (p % 7) * 8 + (pix & 7);
  const float* src = x + ((size_t)((n * HH + y) * WWI + xx)) * CDIM + c8;
  float4 v0 = *(const float4*)src, v1 = *(const float4*)(src + 4);
  float vv[8] = {v0.x, v0.y, v0.z, v0.w, v1.x, v1.y, v1.z, v1.w};
  u16x8 Hh, Ll;
#pragma unroll
  for (int i = 0; i < 8; i++) {
    u16 h = f2bf(vv[i]); Hh[i] = h; Ll[i] = f2bf(vv[i] - bf2f(h));
  }
  u16* dst = A1 + (size_t)r * 1024;
  *(u16x8*)(dst + c8)       = Hh;
  *(u16x8*)(dst + 512 + c8) = Ll;
}

// ---- weight prep 3-term: [rows][512] f32 -> [rows][1536] bf16 = [Bh | Bh | Bl] ----
__global__ __launch_bounds__(256) void k_prep_b(const float* __restrict__ w, u16* __restrict__ Bq) {
  int t = blockIdx.x * 256 + threadIdx.x;
  int r = t >> 6, c8 = (t & 63) << 3;
  const float* src = w + (size_t)r * CDIM + c8;
  float4 v0 = *(const float4*)src, v1 = *(const float4*)(src + 4);
  float vv[8] = {v0.x, v0.y, v0.z, v0.w, v1.x, v1.y, v1.z, v1.w};
  u16x8 Hh, Ll;
#pragma unroll
  for (int i = 0; i < 8; i++) {
    u16 h = f2bf(vv[i]); Hh[i] = h; Ll[i] = f2bf(vv[i] - bf2f(h));
  }
  u16* dst = Bq + (size_t)r * CQKV;
  *(u16x8*)(dst + c8)        = Hh;
  *(u16x8*)(dst + 512 + c8)  = Hh;
  *(u16x8*)(dst + 1024 + c8) = Ll;
}

// ---- weight prep 2-term (v): qkv_w rows 1024.. -> [512][1024] bf16 = [Bh | Bh] ----
__global__ __launch_bounds__(256) void k_prep_bv(const float* __restrict__ w, u16* __restrict__ Bq) {
  int t = blockIdx.x * 256 + threadIdx.x;
  int r = t >> 6, c8 = (t & 63) << 3;
  const float* src = w + (size_t)(1024 + r) * CDIM + c8;
  float4 v0 = *(const float4*)src, v1 = *(const float4*)(src + 4);
  float vv[8] = {v0.x, v0.y, v0.z, v0.w, v1.x, v1.y, v1.z, v1.w};
  u16x8 Hh;
#pragma unroll
  for (int i = 0; i < 8; i++) Hh[i] = f2bf(vv[i]);
  u16* dst = Bq + (size_t)r * 1024;
  *(u16x8*)(dst + c8)       = Hh;
  *(u16x8*)(dst + 512 + c8) = Hh;
}

// ---- LePE weight transpose: lepe_w [512][9] f32 -> lwt [9][512] f32 ----
__global__ __launch_bounds__(256) void k_prep_lw(const float* __restrict__ lw, float* __restrict__ lwt) {
  int idx = blockIdx.x * 256 + threadIdx.x;   // 0..4607
  int tap = idx >> 9, ch = idx & 511;
  lwt[idx] = lw[ch * 9 + tap];
}

// ---- GEMM -> bf16 qkvh slab. A is [M][1024]=[Ah|Al], K-index wraps at 1024.
//      XCD-aware by-major block remap; 16B-chunk XOR LDS swizzle (src-side + read).
//      Optional: window-mean epilogue (qw/kw, routing) ; transposed V store (vTp). ----
__global__ __launch_bounds__(256) void k_gemm_h(const u16* __restrict__ A,
                                                const u16* __restrict__ B, int ldb, int K, int nbn,
                                                const float* __restrict__ bias,
                                                u16* __restrict__ qkvh, int coloff,
                                                float* __restrict__ qw, float* __restrict__ kw,
                                                u16* __restrict__ vTp) {
  __shared__ u16 As[128 * 32];
  __shared__ u16 Bs[128 * 32];
  // XCD-aware: same-by blocks consecutive on one XCD (grid % 8 == 0)
  int cpx = gridDim.x >> 3;
  int o = blockIdx.x;
  int w = (o & 7) * cpx + (o >> 3);
  int bx = w % nbn, by = w / nbn;
  int tid = threadIdx.x, lane = tid & 63, wid = tid >> 6;
  int wr = (wid >> 1) << 6, wc = (wid & 1) << 6;
  int l15 = lane & 15, h4 = lane >> 4;
  int srow = tid >> 2;
  int ssw  = ((tid ^ srow) & 3) << 3;   // swizzled source chunk (u16 units)
  int sx   = ((h4 ^ l15) & 3) << 4;     // swizzled read chunk (bytes)
  const u16* Ab = A + (size_t)(by << 7) * 1024;
  const u16* Bb = B + (size_t)(bx << 7) * ldb;
  f32x4 acc[4][4] = {};
  for (int k0 = 0; k0 < K; k0 += 32) {
    int ka = (k0 < 1024) ? k0 : (k0 - 1024);
    gld16(Ab + (size_t)srow * 1024 + ka + ssw,        (char*)As + tid * 16);
    gld16(Ab + (size_t)(srow + 64) * 1024 + ka + ssw, (char*)As + 4096 + tid * 16);
    gld16(Bb + (size_t)srow * ldb + k0 + ssw,         (char*)Bs + tid * 16);
    gld16(Bb + (size_t)(srow + 64) * ldb + k0 + ssw,  (char*)Bs + 4096 + tid * 16);
    __syncthreads();
    s16x8 af[4], bfr[4];
#pragma unroll
    for (int f = 0; f < 4; f++) af[f]  = *(const s16x8*)((const char*)As + (wr + f * 16 + l15) * 64 + sx);
#pragma unroll
    for (int f = 0; f < 4; f++) bfr[f] = *(const s16x8*)((const char*)Bs + (wc + f * 16 + l15) * 64 + sx);
#pragma unroll
    for (int i = 0; i < 4; i++)
#pragma unroll
      for (int j = 0; j < 4; j++)
        acc[i][j] = __builtin_amdgcn_mfma_f32_16x16x32_bf16(af[i], bfr[j], acc[i][j], 0, 0, 0);
    __syncthreads();
  }
#pragma unroll
  for (int i = 0; i < 4; i++) {
#pragma unroll
    for (int j = 0; j < 4; j++) {
      int col = (bx << 7) + wc + j * 16 + l15;
      float bcol = bias[col];
      u16x4 pk;
#pragma unroll
      for (int rg = 0; rg < 4; rg++) {
        int row = (by << 7) + wr + i * 16 + (h4 << 2) + rg;
        u16 hv = f2bf(acc[i][j][rg] + bcol);
        qkvh[(size_t)row * CQKV + coloff + col] = hv;
        pk[rg] = hv;
      }
      if (vTp) {
        int row0 = (by << 7) + wr + i * 16 + (h4 << 2);
        *(u16x4*)(vTp + (size_t)col * NROWS + row0) = pk;
      }
    }
  }
  if (qw) {   // window means from f32 accumulators (routing precision)
    int np = (by << 1) + (wr >> 6);
#pragma unroll
    for (int j = 0; j < 4; j++) {
      float s = 0.f;
#pragma unroll
      for (int i = 0; i < 4; i++)
#pragma unroll
        for (int rg = 0; rg < 4; rg++) s += acc[i][j][rg];
      s += __shfl_xor(s, 16);
      s += __shfl_xor(s, 32);
      int col = (bx << 7) + wc + j * 16 + l15;
      if (h4 == 0) {
        float mv = s * (1.f / 64.f) + bias[col];
        if (col < 512) qw[(size_t)np * 512 + col] = mv;
        else           kw[(size_t)np * 512 + (col - 512)] = mv;
      }
    }
  }
}

// ---- GEMM2: C(f32, spatial layout) = A2([M][1024] wrap) @ B2^T + bias ----
__global__ __launch_bounds__(256) void k_gemm_out(const u16* __restrict__ A, const u16* __restrict__ B,
                                                  float* __restrict__ C, const float* __restrict__ bias) {
  __shared__ u16 As[128 * 32];
  __shared__ u16 Bs[128 * 32];
  const int K = CQKV, N = CDIM;
  int cpx = gridDim.x >> 3;
  int o = blockIdx.x;
  int w = (o & 7) * cpx + (o >> 3);
  int bx = w & 3, by = w >> 2;
  int tid = threadIdx.x, lane = tid & 63, wid = tid >> 6;
  int wr = (wid >> 1) << 6, wc = (wid & 1) << 6;
  int l15 = lane & 15, h4 = lane >> 4;
  int srow = tid >> 2;
  int ssw  = ((tid ^ srow) & 3) << 3;
  int sx   = ((h4 ^ l15) & 3) << 4;
  const u16* Ab = A + (size_t)(by << 7) * 1024;
  const u16* Bb = B + (size_t)(bx << 7) * K;
  f32x4 acc[4][4] = {};
  for (int k0 = 0; k0 < K; k0 += 32) {
    int ka = (k0 < 1024) ? k0 : (k0 - 1024);
    gld16(Ab + (size_t)srow * 1024 + ka + ssw,        (char*)As + tid * 16);
    gld16(Ab + (size_t)(srow + 64) * 1024 + ka + ssw, (char*)As + 4096 + tid * 16);
    gld16(Bb + (size_t)srow * K + k0 + ssw,           (char*)Bs + tid * 16);
    gld16(Bb + (size_t)(srow + 64) * K + k0 + ssw,    (char*)Bs + 4096 + tid * 16);
    __syncthreads();
    s16x8 af[4], bfr[4];
#pragma unroll
    for (int f = 0; f < 4; f++) af[f]  = *(const s16x8*)((const char*)As + (wr + f * 16 + l15) * 64 + sx);
#pragma unroll
    for (int f = 0; f < 4; f++) bfr[f] = *(const s16x8*)((const char*)Bs + (wc + f * 16 + l15) * 64 + sx);
#pragma unroll
    for (int i = 0; i < 4; i++)
#pragma unroll
      for (int j = 0; j < 4; j++)
        acc[i][j] = __builtin_amdgcn_mfma_f32_16x16x32_bf16(af[i], bfr[j], acc[i][j], 0, 0, 0);
    __syncthreads();
  }
#pragma unroll
  for (int i = 0; i < 4; i++) {
#pragma unroll
    for (int j = 0; j < 4; j++) {
      int col = (bx << 7) + wc + j * 16 + l15;
      float bcol = bias[col];
#pragma unroll
      for (int rg = 0; rg < 4; rg++) {
        int row = (by << 7) + wr + i * 16 + (h4 << 2) + rg;
        int n = row / (P2C * 64); int rem = row - n * (P2C * 64);
        int p = rem >> 6, pix = rem & 63;
        int y = (p / 7) * 8 + (pix >> 3), xx = (p % 7) * 8 + (pix & 7);
        C[(size_t)((n * HH + y) * WWI + xx) * N + col] = acc[i][j][rg] + bcol;
      }
    }
  }
}

// ---- routing: per (n,p) 49 logits from f32 window means, top-4 (stable ties) ----
__global__ __launch_bounds__(64) void k_route(const float* __restrict__ qw,
                                              const float* __restrict__ kw, int* __restrict__ ridx) {
  int np = blockIdx.x, n = np / P2C;
  int t = threadIdx.x;
  __shared__ float qrow[512];
  __shared__ float logit[64];
  for (int c = t; c < 512; c += 64) qrow[c] = qw[(size_t)np * 512 + c];
  __syncthreads();
  if (t < P2C) {
    const float* kr = kw + (size_t)(n * P2C + t) * 512;
    float s = 0.f;
    for (int c = 0; c < 512; c++) s += qrow[c] * kr[c];
    logit[t] = s;
  }
  __syncthreads();
  if (t == 0) {
    for (int tt = 0; tt < 4; tt++) {
      float best = -1e30f; int bi = 0;
      for (int q = 0; q < P2C; q++) if (logit[q] > best) { best = logit[q]; bi = q; }
      ridx[np * 4 + tt] = bi;
      logit[bi] = -1e30f;
    }
  }
}

// ---- LePE depthwise 3x3 (zero pad), transposed weights lwt[9][512] (coalesced) ----
__global__ __launch_bounds__(256) void k_lepe(const u16* __restrict__ qkvh,
                                              const float* __restrict__ lwt, const float* __restrict__ lb,
                                              u16* __restrict__ lepe) {
  int t = blockIdx.x * 256 + threadIdx.x;
  int r = t >> 6, c8 = (t & 63) << 3;
  int n = r / (P2C * 64); int rem = r - n * (P2C * 64);
  int p = rem >> 6, pix = rem & 63;
  int y = (p / 7) * 8 + (pix >> 3), xx = (p % 7) * 8 + (pix & 7);
  float acc[8];
  {
    float4 b0 = *(const float4*)(lb + c8), b1 = *(const float4*)(lb + c8 + 4);
    acc[0]=b0.x; acc[1]=b0.y; acc[2]=b0.z; acc[3]=b0.w;
    acc[4]=b1.x; acc[5]=b1.y; acc[6]=b1.z; acc[7]=b1.w;
  }
#pragma unroll
  for (int dy = -1; dy <= 1; dy++) {
#pragma unroll
    for (int dx = -1; dx <= 1; dx++) {
      int yy = y + dy, xz = xx + dx;
      if (yy < 0 || yy >= HH || xz < 0 || xz >= WWI) continue;
      int tap = (dy + 1) * 3 + (dx + 1);
      int p2 = (yy >> 3) * 7 + (xz >> 3), px2 = (yy & 7) * 8 + (xz & 7);
      const u16* v = qkvh + ((size_t)((n * P2C + p2) * 64 + px2)) * CQKV + 1024 + c8;
      u16x8 a = *(const u16x8*)v;
      const float* wrow = lwt + tap * 512 + c8;
      float4 w0 = *(const float4*)wrow, w1 = *(const float4*)(wrow + 4);
      float ww[8] = {w0.x, w0.y, w0.z, w0.w, w1.x, w1.y, w1.z, w1.w};
#pragma unroll
      for (int i = 0; i < 8; i++) acc[i] += bf2f(a[i]) * ww[i];
    }
  }
  u16x8 o;
#pragma unroll
  for (int i = 0; i < 8; i++) o[i] = f2bf(acc[i]);
  *(u16x8*)(lepe + (size_t)r * CDIM + c8) = o;
}

// ---- attention: block=(np, head-quad), wave=head. Swapped S^T=K*Q^T.
//      K frags hoisted (global, fq-independent). V staged in LDS (64KB) from vT:
//      512 strips of 128B ([colL][w][64 keys]), 16B-chunk XOR swizzle (src-side),
//      per-lane V frags = 2x 8B ds_read. softmax exp2(fma); P->bf16 cvt_pk.
//      Epilogue: + lepe, write A2 [hi|lo] (1024 wide). ----
__global__ __launch_bounds__(256) void k_attn(const u16* __restrict__ qkvh,
                                              const u16* __restrict__ vT,
                                              const int* __restrict__ ridx,
                                              const u16* __restrict__ lepe, u16* __restrict__ A2) {
  __shared__ u16 Vs[32768];    // 64 KB
  int b = blockIdx.x;
  int mq = b & 3, np = b >> 2;
  int n = np / P2C;
  int tid = threadIdx.x;
  int wid = tid >> 6, lane = tid & 63;
  int m = (mq << 2) + wid;
  int l15 = lane & 15, h4 = lane >> 4;
  int krow[4];
#pragma unroll
  for (int w = 0; w < 4; w++) krow[w] = (n * P2C + ridx[np * 4 + w]) * 64;
  size_t qrow0 = (size_t)np * 64;
  union FR  { s16x8 s; u16 u[8]; };
  union FRu { s16x8 s; unsigned w[4]; };
  f32x4 zero = {0.f, 0.f, 0.f, 0.f};
  // ---- stage V into LDS: chunk ch (16B) -> strip=ch>>3 (colL=strip>>2, w=strip&3),
  //      dest chunk c16d=ch&7 holds source chunk c16d ^ (colL&7)
  int colbase = mq << 7;
#pragma unroll
  for (int i = 0; i < 16; i++) {
    int ch = i * 256 + tid;
    int strip = ch >> 3, c16d = ch & 7;
    int colL = strip >> 2, w = strip & 3;
    int c16s = c16d ^ (colL & 7);
    gld16(vT + (size_t)(colbase + colL) * NROWS + krow[w] + c16s * 8, (char*)Vs + ch * 16);
  }
  // hoisted K fragments (fq-independent)
  FR kf[16];
#pragma unroll
  for (int fk = 0; fk < 16; fk++) {
    int key = fk * 16 + l15;
    kf[fk].s = *(const s16x8*)(qkvh + (size_t)(krow[key >> 6] + (key & 63)) * CQKV + 512 + m * 32 + h4 * 8);
  }
  __syncthreads();
#pragma unroll
  for (int fq = 0; fq < 4; fq++) {
    s16x8 qf = *(const s16x8*)(qkvh + (qrow0 + fq * 16 + l15) * CQKV + m * 32 + h4 * 8);
    f32x4 st[16];
#pragma unroll
    for (int fk = 0; fk < 16; fk++)
      st[fk] = __builtin_amdgcn_mfma_f32_16x16x32_bf16(kf[fk].s, qf, zero, 0, 0, 0);
    float mx = -1e30f;
#pragma unroll
    for (int fk = 0; fk < 16; fk++)
#pragma unroll
      for (int rg = 0; rg < 4; rg++) mx = fmaxf(mx, st[fk][rg]);
    mx = fmaxf(mx, __shfl_xor(mx, 16));
    mx = fmaxf(mx, __shfl_xor(mx, 32));
    float nmc = -mx * SC_LOG2E;
    float sum = 0.f;
#pragma unroll
    for (int fk = 0; fk < 16; fk++)
#pragma unroll
      for (int rg = 0; rg < 4; rg++) {
        float e = exp2f(fmaf(st[fk][rg], SC_LOG2E, nmc));
        st[fk][rg] = e; sum += e;
      }
    sum += __shfl_xor(sum, 16);
    sum += __shfl_xor(sum, 32);
    f32x4 oacc[2] = {zero, zero};
#pragma unroll
    for (int s8 = 0; s8 < 8; s8++) {
      FRu pa;
      pa.w[0] = cvtpk(st[2 * s8][0],     st[2 * s8][1]);
      pa.w[1] = cvtpk(st[2 * s8][2],     st[2 * s8][3]);
      pa.w[2] = cvtpk(st[2 * s8 + 1][0], st[2 * s8 + 1][1]);
      pa.w[3] = cvtpk(st[2 * s8 + 1][2], st[2 * s8 + 1][3]);
      int wv = s8 >> 1;
      int c16 = ((s8 & 1) << 2) + (h4 >> 1);
      int lo8 = (h4 & 1) << 3;
#pragma unroll
      for (int fd = 0; fd < 2; fd++) {
        int colL = (wid << 5) + (fd << 4) + l15;
        int strip = (colL << 2) + wv;
        int swz = colL & 7;
        const char* base = (const char*)Vs + strip * 128 + lo8;
        FR vf;
        *(u16x4*)&vf.u[0] = *(const u16x4*)(base + ((c16 ^ swz) << 4));
        *(u16x4*)&vf.u[4] = *(const u16x4*)(base + (((c16 + 2) ^ swz) << 4));
        oacc[fd] = __builtin_amdgcn_mfma_f32_16x16x32_bf16(pa.s, vf.s, oacc[fd], 0, 0, 0);
      }
    }
#pragma unroll
    for (int rg = 0; rg < 4; rg++) {
      float sq = __shfl(sum, (h4 << 2) + rg);
      int q = fq * 16 + (h4 << 2) + rg;
#pragma unroll
      for (int fd = 0; fd < 2; fd++) {
        int col = m * 32 + fd * 16 + l15;
        size_t row = qrow0 + q;
        float val = oacc[fd][rg] / sq + bf2f(lepe[row * CDIM + col]);
        u16 hi = f2bf(val);
        u16 lo = f2bf(val - bf2f(hi));
        A2[row * 1024 + col]       = hi;
        A2[row * 1024 + 512 + col] = lo;
      }
    }
  }
}

extern "C" void kernel_launch(void* const* d_in, const int* in_sizes, int n_in,
                              void* d_out, int out_size, void* d_ws, size_t ws_size,
                              hipStream_t stream) {
  (void)in_sizes; (void)n_in; (void)out_size; (void)ws_size;
  const float* x      = (const float*)d_in[0];
  const float* qkv_w  = (const float*)d_in[1];
  const float* qkv_b  = (const float*)d_in[2];
  const float* wo_w   = (const float*)d_in[3];
  const float* wo_b   = (const float*)d_in[4];
  const float* lepe_w = (const float*)d_in[5];
  const float* lepe_b = (const float*)d_in[6];
  float* out = (float*)d_out;
  char* ws = (char*)d_ws;
  size_t off = 0;
  auto alc = [&](size_t b) { char* p = ws + off; off += (b + 255) & ~(size_t)255; return p; };
  u16*   B1    = (u16*)  alc((size_t)1024 * CQKV * 2);        //  3.1 MB  (q,k rows, 3-term)
  u16*   Bv    = (u16*)  alc((size_t)512 * 1024 * 2);         //  1.0 MB  (v rows, 2-term)
  u16*   B2    = (u16*)  alc((size_t)CDIM * CQKV * 2);        //  1.6 MB
  float* lwt   = (float*)alc((size_t)9 * 512 * 4);            //  18 KB
  u16*   qkvh  = (u16*)  alc((size_t)NROWS * CQKV * 2);       // 77.1 MB
  u16*   vT    = (u16*)  alc((size_t)CDIM * NROWS * 2);       // 25.7 MB (v transposed)
  float* qw    = (float*)alc((size_t)NB * P2C * CDIM * 4);    //  0.8 MB
  float* kw    = (float*)alc((size_t)NB * P2C * CDIM * 4);    //  0.8 MB
  int*   ridx  = (int*)  alc((size_t)NB * P2C * 4 * 4);       //  6 KB
  u16*   lepe  = (u16*)  alc((size_t)NROWS * CDIM * 2);       // 25.7 MB
  u16*   A12   = (u16*)  alc((size_t)NROWS * 1024 * 2);       // 51.4 MB (A1, later A2)
  // total ~187 MB

  k_prep_a1<<<dim3(6272), dim3(256), 0, stream>>>(x, A12);
  k_prep_b <<<dim3(256),  dim3(256), 0, stream>>>(qkv_w, B1);     // rows 0..1023 (q,k)
  k_prep_bv<<<dim3(128),  dim3(256), 0, stream>>>(qkv_w, Bv);     // rows 1024..1535 (v)
  k_prep_b <<<dim3(128),  dim3(256), 0, stream>>>(wo_w, B2);
  k_prep_lw<<<dim3(18),   dim3(256), 0, stream>>>(lepe_w, lwt);
  k_gemm_h <<<dim3(1568), dim3(256), 0, stream>>>(A12, B1, CQKV, CQKV, 8,
                                                  qkv_b, qkvh, 0, qw, kw, nullptr);
  k_gemm_h <<<dim3(784),  dim3(256), 0, stream>>>(A12, Bv, 1024, 1024, 4,
                                                  qkv_b + 1024, qkvh, 1024, nullptr, nullptr, vT);
  k_route <<<dim3(392),  dim3(64),  0, stream>>>(qw, kw, ridx);
  k_lepe  <<<dim3(6272), dim3(256), 0, stream>>>(qkvh, lwt, lepe_b, lepe);
  k_attn  <<<dim3(1568), dim3(256), 0, stream>>>(qkvh, vT, ridx, lepe, A12);
  k_gemm_out<<<dim3(784), dim3(256), 0, stream>>>(A12, B2, out, wo_b);
}

// Round 8
// 475.957 us; speedup vs baseline: 1.5346x; 1.0140x over previous
//
#include <hip/hip_runtime.h>

typedef unsigned short u16;
typedef __attribute__((ext_vector_type(8))) short  s16x8;
typedef __attribute__((ext_vector_type(8))) u16    u16x8;
typedef __attribute__((ext_vector_type(4))) u16    u16x4;
typedef __attribute__((ext_vector_type(4))) float  f32x4;

#define NB    8
#define HH    56
#define WWI   56
#define CDIM  512
#define CQKV  1536
#define P2C   49
#define NROWS (NB*P2C*64)      // 25088 windowed pixel rows
// SCALE * log2(e)
#define SC_LOG2E 0.06375871682f

__device__ __forceinline__ u16 f2bf(float f) {
  union { float f; unsigned u; } x; x.f = f;
  unsigned r = x.u + 0x7fffu + ((x.u >> 16) & 1u);
  return (u16)(r >> 16);
}
__device__ __forceinline__ float bf2f(u16 h) {
  union { unsigned u; float f; } x; x.u = ((unsigned)h) << 16;
  return x.f;
}
__device__ __forceinline__ unsigned cvtpk(float lo, float hi) {
  unsigned d;
  asm("v_cvt_pk_bf16_f32 %0, %1, %2" : "=v"(d) : "v"(lo), "v"(hi));
  return d;
}

__device__ __forceinline__ void gld16(const void* g, void* l) {
  __builtin_amdgcn_global_load_lds((const __attribute__((address_space(1))) void*)g,
                                   (__attribute__((address_space(3))) void*)l, 16, 0, 0);
}

// ---- A1 prep: x (NHWC f32) -> windowed [25088][1024] bf16 = [Ah | Al] ----
__global__ __launch_bounds__(256) void k_prep_a1(const float* __restrict__ x, u16* __restrict__ A1) {
  int t = blockIdx.x * 256 + threadIdx.x;
  int r = t >> 6, c8 = (t & 63) << 3;
  int n = r / (P2C * 64); int rem = r - n * (P2C * 64);
  int p = rem >> 6, pix = rem & 63;
  int y = (p / 7) * 8 + (pix >> 3), xx = (p % 7) * 8 + (pix & 7);
  const float* src = x + ((size_t)((n * HH + y) * WWI + xx)) * CDIM + c8;
  float4 v0 = *(const float4*)src, v1 = *(const float4*)(src + 4);
  float vv[8] = {v0.x, v0.y, v0.z, v0.w, v1.x, v1.y, v1.z, v1.w};
  u16x8 Hh, Ll;
#pragma unroll
  for (int i = 0; i < 8; i++) {
    u16 h = f2bf(vv[i]); Hh[i] = h; Ll[i] = f2bf(vv[i] - bf2f(h));
  }
  u16* dst = A1 + (size_t)r * 1024;
  *(u16x8*)(dst + c8)       = Hh;
  *(u16x8*)(dst + 512 + c8) = Ll;
}

// ---- weight prep 3-term: [rows][512] f32 -> [rows][1536] bf16 = [Bh | Bh | Bl] ----
__global__ __launch_bounds__(256) void k_prep_b(const float* __restrict__ w, u16* __restrict__ Bq) {
  int t = blockIdx.x * 256 + threadIdx.x;
  int r = t >> 6, c8 = (t & 63) << 3;
  const float* src = w + (size_t)r * CDIM + c8;
  float4 v0 = *(const float4*)src, v1 = *(const float4*)(src + 4);
  float vv[8] = {v0.x, v0.y, v0.z, v0.w, v1.x, v1.y, v1.z, v1.w};
  u16x8 Hh, Ll;
#pragma unroll
  for (int i = 0; i < 8; i++) {
    u16 h = f2bf(vv[i]); Hh[i] = h; Ll[i] = f2bf(vv[i] - bf2f(h));
  }
  u16* dst = Bq + (size_t)r * CQKV;
  *(u16x8*)(dst + c8)        = Hh;
  *(u16x8*)(dst + 512 + c8)  = Hh;
  *(u16x8*)(dst + 1024 + c8) = Ll;
}

// ---- weight prep 2-term (v): qkv_w rows 1024.. -> [512][1024] bf16 = [Bh | Bh] ----
__global__ __launch_bounds__(256) void k_prep_bv(const float* __restrict__ w, u16* __restrict__ Bq) {
  int t = blockIdx.x * 256 + threadIdx.x;
  int r = t >> 6, c8 = (t & 63) << 3;
  const float* src = w + (size_t)(1024 + r) * CDIM + c8;
  float4 v0 = *(const float4*)src, v1 = *(const float4*)(src + 4);
  float vv[8] = {v0.x, v0.y, v0.z, v0.w, v1.x, v1.y, v1.z, v1.w};
  u16x8 Hh;
#pragma unroll
  for (int i = 0; i < 8; i++) Hh[i] = f2bf(vv[i]);
  u16* dst = Bq + (size_t)r * 1024;
  *(u16x8*)(dst + c8)       = Hh;
  *(u16x8*)(dst + 512 + c8) = Hh;
}

// ---- LePE weight transpose: lepe_w [512][9] f32 -> lwt [9][512] f32 ----
__global__ __launch_bounds__(256) void k_prep_lw(const float* __restrict__ lw, float* __restrict__ lwt) {
  int idx = blockIdx.x * 256 + threadIdx.x;   // 0..4607
  int tap = idx >> 9, ch = idx & 511;
  lwt[idx] = lw[ch * 9 + tap];
}

// ---- GEMM -> bf16 qkvh slab. A is [M][1024]=[Ah|Al], K-index wraps at 1024.
//      XCD-aware by-major block remap; 16B-chunk XOR LDS swizzle (src-side + read).
//      Optional: window-mean epilogue (qw/kw, routing) ; transposed V store (vTp). ----
__global__ __launch_bounds__(256) void k_gemm_h(const u16* __restrict__ A,
                                                const u16* __restrict__ B, int ldb, int K, int nbn,
                                                const float* __restrict__ bias,
                                                u16* __restrict__ qkvh, int coloff,
                                                float* __restrict__ qw, float* __restrict__ kw,
                                                u16* __restrict__ vTp) {
  __shared__ u16 As[128 * 32];
  __shared__ u16 Bs[128 * 32];
  // XCD-aware: same-by blocks consecutive on one XCD (grid % 8 == 0)
  int cpx = gridDim.x >> 3;
  int o = blockIdx.x;
  int w = (o & 7) * cpx + (o >> 3);
  int bx = w % nbn, by = w / nbn;
  int tid = threadIdx.x, lane = tid & 63, wid = tid >> 6;
  int wr = (wid >> 1) << 6, wc = (wid & 1) << 6;
  int l15 = lane & 15, h4 = lane >> 4;
  int srow = tid >> 2;
  int ssw  = ((tid ^ srow) & 3) << 3;   // swizzled source chunk (u16 units)
  int sx   = ((h4 ^ l15) & 3) << 4;     // swizzled read chunk (bytes)
  const u16* Ab = A + (size_t)(by << 7) * 1024;
  const u16* Bb = B + (size_t)(bx << 7) * ldb;
  f32x4 acc[4][4] = {};
  for (int k0 = 0; k0 < K; k0 += 32) {
    int ka = (k0 < 1024) ? k0 : (k0 - 1024);
    gld16(Ab + (size_t)srow * 1024 + ka + ssw,        (char*)As + tid * 16);
    gld16(Ab + (size_t)(srow + 64) * 1024 + ka + ssw, (char*)As + 4096 + tid * 16);
    gld16(Bb + (size_t)srow * ldb + k0 + ssw,         (char*)Bs + tid * 16);
    gld16(Bb + (size_t)(srow + 64) * ldb + k0 + ssw,  (char*)Bs + 4096 + tid * 16);
    __syncthreads();
    s16x8 af[4], bfr[4];
#pragma unroll
    for (int f = 0; f < 4; f++) af[f]  = *(const s16x8*)((const char*)As + (wr + f * 16 + l15) * 64 + sx);
#pragma unroll
    for (int f = 0; f < 4; f++) bfr[f] = *(const s16x8*)((const char*)Bs + (wc + f * 16 + l15) * 64 + sx);
#pragma unroll
    for (int i = 0; i < 4; i++)
#pragma unroll
      for (int j = 0; j < 4; j++)
        acc[i][j] = __builtin_amdgcn_mfma_f32_16x16x32_bf16(af[i], bfr[j], acc[i][j], 0, 0, 0);
    __syncthreads();
  }
#pragma unroll
  for (int i = 0; i < 4; i++) {
#pragma unroll
    for (int j = 0; j < 4; j++) {
      int col = (bx << 7) + wc + j * 16 + l15;
      float bcol = bias[col];
      u16x4 pk;
#pragma unroll
      for (int rg = 0; rg < 4; rg++) {
        int row = (by << 7) + wr + i * 16 + (h4 << 2) + rg;
        u16 hv = f2bf(acc[i][j][rg] + bcol);
        qkvh[(size_t)row * CQKV + coloff + col] = hv;
        pk[rg] = hv;
      }
      if (vTp) {
        int row0 = (by << 7) + wr + i * 16 + (h4 << 2);
        *(u16x4*)(vTp + (size_t)col * NROWS + row0) = pk;
      }
    }
  }
  if (qw) {   // window means from f32 accumulators (routing precision)
    int np = (by << 1) + (wr >> 6);
#pragma unroll
    for (int j = 0; j < 4; j++) {
      float s = 0.f;
#pragma unroll
      for (int i = 0; i < 4; i++)
#pragma unroll
        for (int rg = 0; rg < 4; rg++) s += acc[i][j][rg];
      s += __shfl_xor(s, 16);
      s += __shfl_xor(s, 32);
      int col = (bx << 7) + wc + j * 16 + l15;
      if (h4 == 0) {
        float mv = s * (1.f / 64.f) + bias[col];
        if (col < 512) qw[(size_t)np * 512 + col] = mv;
        else           kw[(size_t)np * 512 + (col - 512)] = mv;
      }
    }
  }
}

// ---- GEMM2: C(f32, spatial layout) = A2([M][1024] wrap) @ B2^T + bias ----
__global__ __launch_bounds__(256) void k_gemm_out(const u16* __restrict__ A, const u16* __restrict__ B,
                                                  float* __restrict__ C, const float* __restrict__ bias) {
  __shared__ u16 As[128 * 32];
  __shared__ u16 Bs[128 * 32];
  const int K = CQKV, N = CDIM;
  int cpx = gridDim.x >> 3;
  int o = blockIdx.x;
  int w = (o & 7) * cpx + (o >> 3);
  int bx = w & 3, by = w >> 2;
  int tid = threadIdx.x, lane = tid & 63, wid = tid >> 6;
  int wr = (wid >> 1) << 6, wc = (wid & 1) << 6;
  int l15 = lane & 15, h4 = lane >> 4;
  int srow = tid >> 2;
  int ssw  = ((tid ^ srow) & 3) << 3;
  int sx   = ((h4 ^ l15) & 3) << 4;
  const u16* Ab = A + (size_t)(by << 7) * 1024;
  const u16* Bb = B + (size_t)(bx << 7) * K;
  f32x4 acc[4][4] = {};
  for (int k0 = 0; k0 < K; k0 += 32) {
    int ka = (k0 < 1024) ? k0 : (k0 - 1024);
    gld16(Ab + (size_t)srow * 1024 + ka + ssw,        (char*)As + tid * 16);
    gld16(Ab + (size_t)(srow + 64) * 1024 + ka + ssw, (char*)As + 4096 + tid * 16);
    gld16(Bb + (size_t)srow * K + k0 + ssw,           (char*)Bs + tid * 16);
    gld16(Bb + (size_t)(srow + 64) * K + k0 + ssw,    (char*)Bs + 4096 + tid * 16);
    __syncthreads();
    s16x8 af[4], bfr[4];
#pragma unroll
    for (int f = 0; f < 4; f++) af[f]  = *(const s16x8*)((const char*)As + (wr + f * 16 + l15) * 64 + sx);
#pragma unroll
    for (int f = 0; f < 4; f++) bfr[f] = *(const s16x8*)((const char*)Bs + (wc + f * 16 + l15) * 64 + sx);
#pragma unroll
    for (int i = 0; i < 4; i++)
#pragma unroll
      for (int j = 0; j < 4; j++)
        acc[i][j] = __builtin_amdgcn_mfma_f32_16x16x32_bf16(af[i], bfr[j], acc[i][j], 0, 0, 0);
    __syncthreads();
  }
#pragma unroll
  for (int i = 0; i < 4; i++) {
#pragma unroll
    for (int j = 0; j < 4; j++) {
      int col = (bx << 7) + wc + j * 16 + l15;
      float bcol = bias[col];
#pragma unroll
      for (int rg = 0; rg < 4; rg++) {
        int row = (by << 7) + wr + i * 16 + (h4 << 2) + rg;
        int n = row / (P2C * 64); int rem = row - n * (P2C * 64);
        int p = rem >> 6, pix = rem & 63;
        int y = (p / 7) * 8 + (pix >> 3), xx = (p % 7) * 8 + (pix & 7);
        C[(size_t)((n * HH + y) * WWI + xx) * N + col] = acc[i][j][rg] + bcol;
      }
    }
  }
}

// ---- routing: per (n,p) 49 logits from f32 window means, top-4 (stable ties) ----
__global__ __launch_bounds__(64) void k_route(const float* __restrict__ qw,
                                              const float* __restrict__ kw, int* __restrict__ ridx) {
  int np = blockIdx.x, n = np / P2C;
  int t = threadIdx.x;
  __shared__ float qrow[512];
  __shared__ float logit[64];
  for (int c = t; c < 512; c += 64) qrow[c] = qw[(size_t)np * 512 + c];
  __syncthreads();
  if (t < P2C) {
    const float* kr = kw + (size_t)(n * P2C + t) * 512;
    float s = 0.f;
    for (int c = 0; c < 512; c++) s += qrow[c] * kr[c];
    logit[t] = s;
  }
  __syncthreads();
  if (t == 0) {
    for (int tt = 0; tt < 4; tt++) {
      float best = -1e30f; int bi = 0;
      for (int q = 0; q < P2C; q++) if (logit[q] > best) { best = logit[q]; bi = q; }
      ridx[np * 4 + tt] = bi;
      logit[bi] = -1e30f;
    }
  }
}

// ---- LePE depthwise 3x3 (zero pad), transposed weights lwt[9][512] (coalesced) ----
__global__ __launch_bounds__(256) void k_lepe(const u16* __restrict__ qkvh,
                                              const float* __restrict__ lwt, const float* __restrict__ lb,
                                              u16* __restrict__ lepe) {
  int t = blockIdx.x * 256 + threadIdx.x;
  int r = t >> 6, c8 = (t & 63) << 3;
  int n = r / (P2C * 64); int rem = r - n * (P2C * 64);
  int p = rem >> 6, pix = rem & 63;
  int y = (p / 7) * 8 + (pix >> 3), xx = (p % 7) * 8 + (pix & 7);
  float acc[8];
  {
    float4 b0 = *(const float4*)(lb + c8), b1 = *(const float4*)(lb + c8 + 4);
    acc[0]=b0.x; acc[1]=b0.y; acc[2]=b0.z; acc[3]=b0.w;
    acc[4]=b1.x; acc[5]=b1.y; acc[6]=b1.z; acc[7]=b1.w;
  }
#pragma unroll
  for (int dy = -1; dy <= 1; dy++) {
#pragma unroll
    for (int dx = -1; dx <= 1; dx++) {
      int yy = y + dy, xz = xx + dx;
      if (yy < 0 || yy >= HH || xz < 0 || xz >= WWI) continue;
      int tap = (dy + 1) * 3 + (dx + 1);
      int p2 = (yy >> 3) * 7 + (xz >> 3), px2 = (yy & 7) * 8 + (xz & 7);
      const u16* v = qkvh + ((size_t)((n * P2C + p2) * 64 + px2)) * CQKV + 1024 + c8;
      u16x8 a = *(const u16x8*)v;
      const float* wrow = lwt + tap * 512 + c8;
      float4 w0 = *(const float4*)wrow, w1 = *(const float4*)(wrow + 4);
      float ww[8] = {w0.x, w0.y, w0.z, w0.w, w1.x, w1.y, w1.z, w1.w};
#pragma unroll
      for (int i = 0; i < 8; i++) acc[i] += bf2f(a[i]) * ww[i];
    }
  }
  u16x8 o;
#pragma unroll
  for (int i = 0; i < 8; i++) o[i] = f2bf(acc[i]);
  *(u16x8*)(lepe + (size_t)r * CDIM + c8) = o;
}

// ---- attention: block=(np, head-quad), wave=head. Swapped S^T=K*Q^T.
//      BOTH K and V staged in LDS (64KB each, 128KB total, 1 block/CU):
//      K: 256 rows x 256B (quad's 128 ch) from qkvh, 16B-chunk XOR swz cd^(row&15);
//      V: 512 strips of 128B from vT, chunk swz c^(colL&7). All staging coalesced
//      global_load_lds, LDS dest linear, swizzle applied on global src + LDS read.
//      softmax exp2(fma); P->bf16 cvt_pk. Epilogue: + lepe, A2 [hi|lo]. ----
__global__ __launch_bounds__(256) void k_attn(const u16* __restrict__ qkvh,
                                              const u16* __restrict__ vT,
                                              const int* __restrict__ ridx,
                                              const u16* __restrict__ lepe, u16* __restrict__ A2) {
  __shared__ u16 Ks[32768];    // 64 KB
  __shared__ u16 Vs[32768];    // 64 KB
  int b = blockIdx.x;
  int mq = b & 3, np = b >> 2;
  int n = np / P2C;
  int tid = threadIdx.x;
  int wid = tid >> 6, lane = tid & 63;
  int m = (mq << 2) + wid;
  int l15 = lane & 15, h4 = lane >> 4;
  int krow[4];
#pragma unroll
  for (int w = 0; w < 4; w++) krow[w] = (n * P2C + ridx[np * 4 + w]) * 64;
  size_t qrow0 = (size_t)np * 64;
  union FR  { s16x8 s; u16 u[8]; };
  union FRu { s16x8 s; unsigned w[4]; };
  f32x4 zero = {0.f, 0.f, 0.f, 0.f};
  int colbase = mq << 7;
  // ---- stage K: row = win*64+key (256 rows x 16 chunks of 16B = quad's 128 ch)
  //      dest chunk cd holds source chunk cd ^ (row&15)
#pragma unroll
  for (int i = 0; i < 16; i++) {
    int ch = i * 256 + tid;
    int row = ch >> 4, cd = ch & 15;
    int cs = cd ^ (row & 15);
    gld16(qkvh + (size_t)(krow[row >> 6] + (row & 63)) * CQKV + 512 + colbase + cs * 8,
          (char*)Ks + ch * 16);
  }
  // ---- stage V: strip = colL*4 + w (128B each), dest chunk c16d = src c16d ^ (colL&7)
#pragma unroll
  for (int i = 0; i < 16; i++) {
    int ch = i * 256 + tid;
    int strip = ch >> 3, c16d = ch & 7;
    int colL = strip >> 2, w = strip & 3;
    int c16s = c16d ^ (colL & 7);
    gld16(vT + (size_t)(colbase + colL) * NROWS + krow[w] + c16s * 8, (char*)Vs + ch * 16);
  }
  __syncthreads();
  // hoisted K fragments from LDS (fq-independent): row = fk*16+l15, chunk (wid*4+h4)^l15
  FR kf[16];
#pragma unroll
  for (int fk = 0; fk < 16; fk++) {
    int row = fk * 16 + l15;
    kf[fk].s = *(const s16x8*)((const char*)Ks + row * 256 + ((((wid << 2) + h4) ^ l15) << 4));
  }
#pragma unroll
  for (int fq = 0; fq < 4; fq++) {
    s16x8 qf = *(const s16x8*)(qkvh + (qrow0 + fq * 16 + l15) * CQKV + m * 32 + h4 * 8);
    f32x4 st[16];
#pragma unroll
    for (int fk = 0; fk < 16; fk++)
      st[fk] = __builtin_amdgcn_mfma_f32_16x16x32_bf16(kf[fk].s, qf, zero, 0, 0, 0);
    float mx = -1e30f;
#pragma unroll
    for (int fk = 0; fk < 16; fk++)
#pragma unroll
      for (int rg = 0; rg < 4; rg++) mx = fmaxf(mx, st[fk][rg]);
    mx = fmaxf(mx, __shfl_xor(mx, 16));
    mx = fmaxf(mx, __shfl_xor(mx, 32));
    float nmc = -mx * SC_LOG2E;
    float sum = 0.f;
#pragma unroll
    for (int fk = 0; fk < 16; fk++)
#pragma unroll
      for (int rg = 0; rg < 4; rg++) {
        float e = exp2f(fmaf(st[fk][rg], SC_LOG2E, nmc));
        st[fk][rg] = e; sum += e;
      }
    sum += __shfl_xor(sum, 16);
    sum += __shfl_xor(sum, 32);
    f32x4 oacc[2] = {zero, zero};
#pragma unroll
    for (int s8 = 0; s8 < 8; s8++) {
      FRu pa;
      pa.w[0] = cvtpk(st[2 * s8][0],     st[2 * s8][1]);
      pa.w[1] = cvtpk(st[2 * s8][2],     st[2 * s8][3]);
      pa.w[2] = cvtpk(st[2 * s8 + 1][0], st[2 * s8 + 1][1]);
      pa.w[3] = cvtpk(st[2 * s8 + 1][2], st[2 * s8 + 1][3]);
      int wv = s8 >> 1;
      int c16 = ((s8 & 1) << 2) + (h4 >> 1);
      int lo8 = (h4 & 1) << 3;
#pragma unroll
      for (int fd = 0; fd < 2; fd++) {
        int colL = (wid << 5) + (fd << 4) + l15;
        int strip = (colL << 2) + wv;
        int swz = colL & 7;
        const char* base = (const char*)Vs + strip * 128 + lo8;
        FR vf;
        *(u16x4*)&vf.u[0] = *(const u16x4*)(base + ((c16 ^ swz) << 4));
        *(u16x4*)&vf.u[4] = *(const u16x4*)(base + (((c16 + 2) ^ swz) << 4));
        oacc[fd] = __builtin_amdgcn_mfma_f32_16x16x32_bf16(pa.s, vf.s, oacc[fd], 0, 0, 0);
      }
    }
#pragma unroll
    for (int rg = 0; rg < 4; rg++) {
      float sq = __shfl(sum, (h4 << 2) + rg);
      int q = fq * 16 + (h4 << 2) + rg;
#pragma unroll
      for (int fd = 0; fd < 2; fd++) {
        int col = m * 32 + fd * 16 + l15;
        size_t row = qrow0 + q;
        float val = oacc[fd][rg] / sq + bf2f(lepe[row * CDIM + col]);
        u16 hi = f2bf(val);
        u16 lo = f2bf(val - bf2f(hi));
        A2[row * 1024 + col]       = hi;
        A2[row * 1024 + 512 + col] = lo;
      }
    }
  }
}

extern "C" void kernel_launch(void* const* d_in, const int* in_sizes, int n_in,
                              void* d_out, int out_size, void* d_ws, size_t ws_size,
                              hipStream_t stream) {
  (void)in_sizes; (void)n_in; (void)out_size; (void)ws_size;
  const float* x      = (const float*)d_in[0];
  const float* qkv_w  = (const float*)d_in[1];
  const float* qkv_b  = (const float*)d_in[2];
  const float* wo_w   = (const float*)d_in[3];
  const float* wo_b   = (const float*)d_in[4];
  const float* lepe_w = (const float*)d_in[5];
  const float* lepe_b = (const float*)d_in[6];
  float* out = (float*)d_out;
  char* ws = (char*)d_ws;
  size_t off = 0;
  auto alc = [&](size_t b) { char* p = ws + off; off += (b + 255) & ~(size_t)255; return p; };
  u16*   B1    = (u16*)  alc((size_t)1024 * CQKV * 2);        //  3.1 MB  (q,k rows, 3-term)
  u16*   Bv    = (u16*)  alc((size_t)512 * 1024 * 2);         //  1.0 MB  (v rows, 2-term)
  u16*   B2    = (u16*)  alc((size_t)CDIM * CQKV * 2);        //  1.6 MB
  float* lwt   = (float*)alc((size_t)9 * 512 * 4);            //  18 KB
  u16*   qkvh  = (u16*)  alc((size_t)NROWS * CQKV * 2);       // 77.1 MB
  u16*   vT    = (u16*)  alc((size_t)CDIM * NROWS * 2);       // 25.7 MB (v transposed)
  float* qw    = (float*)alc((size_t)NB * P2C * CDIM * 4);    //  0.8 MB
  float* kw    = (float*)alc((size_t)NB * P2C * CDIM * 4);    //  0.8 MB
  int*   ridx  = (int*)  alc((size_t)NB * P2C * 4 * 4);       //  6 KB
  u16*   lepe  = (u16*)  alc((size_t)NROWS * CDIM * 2);       // 25.7 MB
  u16*   A12   = (u16*)  alc((size_t)NROWS * 1024 * 2);       // 51.4 MB (A1, later A2)
  // total ~187 MB

  k_prep_a1<<<dim3(6272), dim3(256), 0, stream>>>(x, A12);
  k_prep_b <<<dim3(256),  dim3(256), 0, stream>>>(qkv_w, B1);     // rows 0..1023 (q,k)
  k_prep_bv<<<dim3(128),  dim3(256), 0, stream>>>(qkv_w, Bv);     // rows 1024..1535 (v)
  k_prep_b <<<dim3(128),  dim3(256), 0, stream>>>(wo_w, B2);
  k_prep_lw<<<dim3(18),   dim3(256), 0, stream>>>(lepe_w, lwt);
  k_gemm_h <<<dim3(1568), dim3(256), 0, stream>>>(A12, B1, CQKV, CQKV, 8,
                                                  qkv_b, qkvh, 0, qw, kw, nullptr);
  k_gemm_h <<<dim3(784),  dim3(256), 0, stream>>>(A12, Bv, 1024, 1024, 4,
                                                  qkv_b + 1024, qkvh, 1024, nullptr, nullptr, vT);
  k_route <<<dim3(392),  dim3(64),  0, stream>>>(qw, kw, ridx);
  k_lepe  <<<dim3(6272), dim3(256), 0, stream>>>(qkvh, lwt, lepe_b, lepe);
  k_attn  <<<dim3(1568), dim3(256), 0, stream>>>(qkvh, vT, ridx, lepe, A12);
  k_gemm_out<<<dim3(784), dim3(256), 0, stream>>>(A12, B2, out, wo_b);
}

// Round 11
// 475.181 us; speedup vs baseline: 1.5371x; 1.0016x over previous
//
#include <hip/hip_runtime.h>

typedef unsigned short u16;
typedef __attribute__((ext_vector_type(8))) short  s16x8;
typedef __attribute__((ext_vector_type(8))) u16    u16x8;
typedef __attribute__((ext_vector_type(4))) u16    u16x4;
typedef __attribute__((ext_vector_type(4))) float  f32x4;

#define NB    8
#define HH    56
#define WWI   56
#define CDIM  512
#define CQKV  1536
#define P2C   49
#define NROWS (NB*P2C*64)      // 25088 windowed pixel rows
// SCALE * log2(e)
#define SC_LOG2E 0.06375871682f

__device__ __forceinline__ u16 f2bf(float f) {
  union { float f; unsigned u; } x; x.f = f;
  unsigned r = x.u + 0x7fffu + ((x.u >> 16) & 1u);
  return (u16)(r >> 16);
}
__device__ __forceinline__ float bf2f(u16 h) {
  union { unsigned u; float f; } x; x.u = ((unsigned)h) << 16;
  return x.f;
}
__device__ __forceinline__ unsigned cvtpk(float lo, float hi) {
  unsigned d;
  asm("v_cvt_pk_bf16_f32 %0, %1, %2" : "=v"(d) : "v"(lo), "v"(hi));
  return d;
}

__device__ __forceinline__ void gld16(const void* g, void* l) {
  __builtin_amdgcn_global_load_lds((const __attribute__((address_space(1))) void*)g,
                                   (__attribute__((address_space(3))) void*)l, 16, 0, 0);
}

// ---- A1 prep: x (NHWC f32) -> windowed [25088][1024] bf16 = [Ah | Al] ----
__global__ __launch_bounds__(256) void k_prep_a1(const float* __restrict__ x, u16* __restrict__ A1) {
  int t = blockIdx.x * 256 + threadIdx.x;
  int r = t >> 6, c8 = (t & 63) << 3;
  int n = r / (P2C * 64); int rem = r - n * (P2C * 64);
  int p = rem >> 6, pix = rem & 63;
  int y = (p / 7) * 8 + (pix >> 3), xx = (p % 7) * 8 + (pix & 7);
  const float* src = x + ((size_t)((n * HH + y) * WWI + xx)) * CDIM + c8;
  float4 v0 = *(const float4*)src, v1 = *(const float4*)(src + 4);
  float vv[8] = {v0.x, v0.y, v0.z, v0.w, v1.x, v1.y, v1.z, v1.w};
  u16x8 Hh, Ll;
#pragma unroll
  for (int i = 0; i < 8; i++) {
    u16 h = f2bf(vv[i]); Hh[i] = h; Ll[i] = f2bf(vv[i] - bf2f(h));
  }
  u16* dst = A1 + (size_t)r * 1024;
  *(u16x8*)(dst + c8)       = Hh;
  *(u16x8*)(dst + 512 + c8) = Ll;
}

// ---- weight prep 3-term: [rows][512] f32 -> [rows][1536] bf16 = [Bh | Bh | Bl] ----
__global__ __launch_bounds__(256) void k_prep_b(const float* __restrict__ w, u16* __restrict__ Bq) {
  int t = blockIdx.x * 256 + threadIdx.x;
  int r = t >> 6, c8 = (t & 63) << 3;
  const float* src = w + (size_t)r * CDIM + c8;
  float4 v0 = *(const float4*)src, v1 = *(const float4*)(src + 4);
  float vv[8] = {v0.x, v0.y, v0.z, v0.w, v1.x, v1.y, v1.z, v1.w};
  u16x8 Hh, Ll;
#pragma unroll
  for (int i = 0; i < 8; i++) {
    u16 h = f2bf(vv[i]); Hh[i] = h; Ll[i] = f2bf(vv[i] - bf2f(h));
  }
  u16* dst = Bq + (size_t)r * CQKV;
  *(u16x8*)(dst + c8)        = Hh;
  *(u16x8*)(dst + 512 + c8)  = Hh;
  *(u16x8*)(dst + 1024 + c8) = Ll;
}

// ---- weight prep 2-term (v): qkv_w rows 1024.. -> [512][1024] bf16 = [Bh | Bh] ----
__global__ __launch_bounds__(256) void k_prep_bv(const float* __restrict__ w, u16* __restrict__ Bq) {
  int t = blockIdx.x * 256 + threadIdx.x;
  int r = t >> 6, c8 = (t & 63) << 3;
  const float* src = w + (size_t)(1024 + r) * CDIM + c8;
  float4 v0 = *(const float4*)src, v1 = *(const float4*)(src + 4);
  float vv[8] = {v0.x, v0.y, v0.z, v0.w, v1.x, v1.y, v1.z, v1.w};
  u16x8 Hh;
#pragma unroll
  for (int i = 0; i < 8; i++) Hh[i] = f2bf(vv[i]);
  u16* dst = Bq + (size_t)r * 1024;
  *(u16x8*)(dst + c8)       = Hh;
  *(u16x8*)(dst + 512 + c8) = Hh;
}

// ---- LePE weight transpose: lepe_w [512][9] f32 -> lwt [9][512] f32 ----
__global__ __launch_bounds__(256) void k_prep_lw(const float* __restrict__ lw, float* __restrict__ lwt) {
  int idx = blockIdx.x * 256 + threadIdx.x;   // 0..4607
  int tap = idx >> 9, ch = idx & 511;
  lwt[idx] = lw[ch * 9 + tap];
}

// ---- GEMM -> bf16 qkvh slab. A is [M][1024]=[Ah|Al], K-index wraps at 1024.
//      XCD-aware by-major block remap; 16B-chunk XOR LDS swizzle (src-side + read).
//      Optional: window-mean epilogue (qw/kw, routing) ; transposed V store (vTp). ----
__global__ __launch_bounds__(256) void k_gemm_h(const u16* __restrict__ A,
                                                const u16* __restrict__ B, int ldb, int K, int nbn,
                                                const float* __restrict__ bias,
                                                u16* __restrict__ qkvh, int coloff,
                                                float* __restrict__ qw, float* __restrict__ kw,
                                                u16* __restrict__ vTp) {
  __shared__ u16 As[128 * 32];
  __shared__ u16 Bs[128 * 32];
  // XCD-aware: same-by blocks consecutive on one XCD (grid % 8 == 0)
  int cpx = gridDim.x >> 3;
  int o = blockIdx.x;
  int w = (o & 7) * cpx + (o >> 3);
  int bx = w % nbn, by = w / nbn;
  int tid = threadIdx.x, lane = tid & 63, wid = tid >> 6;
  int wr = (wid >> 1) << 6, wc = (wid & 1) << 6;
  int l15 = lane & 15, h4 = lane >> 4;
  int srow = tid >> 2;
  int ssw  = ((tid ^ srow) & 3) << 3;   // swizzled source chunk (u16 units)
  int sx   = ((h4 ^ l15) & 3) << 4;     // swizzled read chunk (bytes)
  const u16* Ab = A + (size_t)(by << 7) * 1024;
  const u16* Bb = B + (size_t)(bx << 7) * ldb;
  f32x4 acc[4][4] = {};
  for (int k0 = 0; k0 < K; k0 += 32) {
    int ka = (k0 < 1024) ? k0 : (k0 - 1024);
    gld16(Ab + (size_t)srow * 1024 + ka + ssw,        (char*)As + tid * 16);
    gld16(Ab + (size_t)(srow + 64) * 1024 + ka + ssw, (char*)As + 4096 + tid * 16);
    gld16(Bb + (size_t)srow * ldb + k0 + ssw,         (char*)Bs + tid * 16);
    gld16(Bb + (size_t)(srow + 64) * ldb + k0 + ssw,  (char*)Bs + 4096 + tid * 16);
    __syncthreads();
    s16x8 af[4], bfr[4];
#pragma unroll
    for (int f = 0; f < 4; f++) af[f]  = *(const s16x8*)((const char*)As + (wr + f * 16 + l15) * 64 + sx);
#pragma unroll
    for (int f = 0; f < 4; f++) bfr[f] = *(const s16x8*)((const char*)Bs + (wc + f * 16 + l15) * 64 + sx);
#pragma unroll
    for (int i = 0; i < 4; i++)
#pragma unroll
      for (int j = 0; j < 4; j++)
        acc[i][j] = __builtin_amdgcn_mfma_f32_16x16x32_bf16(af[i], bfr[j], acc[i][j], 0, 0, 0);
    __syncthreads();
  }
#pragma unroll
  for (int i = 0; i < 4; i++) {
#pragma unroll
    for (int j = 0; j < 4; j++) {
      int col = (bx << 7) + wc + j * 16 + l15;
      float bcol = bias[col];
      u16x4 pk;
#pragma unroll
      for (int rg = 0; rg < 4; rg++) {
        int row = (by << 7) + wr + i * 16 + (h4 << 2) + rg;
        u16 hv = f2bf(acc[i][j][rg] + bcol);
        qkvh[(size_t)row * CQKV + coloff + col] = hv;
        pk[rg] = hv;
      }
      if (vTp) {
        int row0 = (by << 7) + wr + i * 16 + (h4 << 2);
        *(u16x4*)(vTp + (size_t)col * NROWS + row0) = pk;
      }
    }
  }
  if (qw) {   // window means from f32 accumulators (routing precision)
    int np = (by << 1) + (wr >> 6);
#pragma unroll
    for (int j = 0; j < 4; j++) {
      float s = 0.f;
#pragma unroll
      for (int i = 0; i < 4; i++)
#pragma unroll
        for (int rg = 0; rg < 4; rg++) s += acc[i][j][rg];
      s += __shfl_xor(s, 16);
      s += __shfl_xor(s, 32);
      int col = (bx << 7) + wc + j * 16 + l15;
      if (h4 == 0) {
        float mv = s * (1.f / 64.f) + bias[col];
        if (col < 512) qw[(size_t)np * 512 + col] = mv;
        else           kw[(size_t)np * 512 + (col - 512)] = mv;
      }
    }
  }
}

// ---- GEMM2: C(f32, spatial layout) = A2([M][1024] wrap) @ B2^T + bias ----
__global__ __launch_bounds__(256) void k_gemm_out(const u16* __restrict__ A, const u16* __restrict__ B,
                                                  float* __restrict__ C, const float* __restrict__ bias) {
  __shared__ u16 As[128 * 32];
  __shared__ u16 Bs[128 * 32];
  const int K = CQKV, N = CDIM;
  int cpx = gridDim.x >> 3;
  int o = blockIdx.x;
  int w = (o & 7) * cpx + (o >> 3);
  int bx = w & 3, by = w >> 2;
  int tid = threadIdx.x, lane = tid & 63, wid = tid >> 6;
  int wr = (wid >> 1) << 6, wc = (wid & 1) << 6;
  int l15 = lane & 15, h4 = lane >> 4;
  int srow = tid >> 2;
  int ssw  = ((tid ^ srow) & 3) << 3;
  int sx   = ((h4 ^ l15) & 3) << 4;
  const u16* Ab = A + (size_t)(by << 7) * 1024;
  const u16* Bb = B + (size_t)(bx << 7) * K;
  f32x4 acc[4][4] = {};
  for (int k0 = 0; k0 < K; k0 += 32) {
    int ka = (k0 < 1024) ? k0 : (k0 - 1024);
    gld16(Ab + (size_t)srow * 1024 + ka + ssw,        (char*)As + tid * 16);
    gld16(Ab + (size_t)(srow + 64) * 1024 + ka + ssw, (char*)As + 4096 + tid * 16);
    gld16(Bb + (size_t)srow * K + k0 + ssw,           (char*)Bs + tid * 16);
    gld16(Bb + (size_t)(srow + 64) * K + k0 + ssw,    (char*)Bs + 4096 + tid * 16);
    __syncthreads();
    s16x8 af[4], bfr[4];
#pragma unroll
    for (int f = 0; f < 4; f++) af[f]  = *(const s16x8*)((const char*)As + (wr + f * 16 + l15) * 64 + sx);
#pragma unroll
    for (int f = 0; f < 4; f++) bfr[f] = *(const s16x8*)((const char*)Bs + (wc + f * 16 + l15) * 64 + sx);
#pragma unroll
    for (int i = 0; i < 4; i++)
#pragma unroll
      for (int j = 0; j < 4; j++)
        acc[i][j] = __builtin_amdgcn_mfma_f32_16x16x32_bf16(af[i], bfr[j], acc[i][j], 0, 0, 0);
    __syncthreads();
  }
#pragma unroll
  for (int i = 0; i < 4; i++) {
#pragma unroll
    for (int j = 0; j < 4; j++) {
      int col = (bx << 7) + wc + j * 16 + l15;
      float bcol = bias[col];
#pragma unroll
      for (int rg = 0; rg < 4; rg++) {
        int row = (by << 7) + wr + i * 16 + (h4 << 2) + rg;
        int n = row / (P2C * 64); int rem = row - n * (P2C * 64);
        int p = rem >> 6, pix = rem & 63;
        int y = (p / 7) * 8 + (pix >> 3), xx = (p % 7) * 8 + (pix & 7);
        C[(size_t)((n * HH + y) * WWI + xx) * N + col] = acc[i][j][rg] + bcol;
      }
    }
  }
}

// ---- routing: per (n,p) 49 logits from f32 window means, top-4 (stable ties) ----
__global__ __launch_bounds__(64) void k_route(const float* __restrict__ qw,
                                              const float* __restrict__ kw, int* __restrict__ ridx) {
  int np = blockIdx.x, n = np / P2C;
  int t = threadIdx.x;
  __shared__ float qrow[512];
  __shared__ float logit[64];
  for (int c = t; c < 512; c += 64) qrow[c] = qw[(size_t)np * 512 + c];
  __syncthreads();
  if (t < P2C) {
    const float* kr = kw + (size_t)(n * P2C + t) * 512;
    float s = 0.f;
    for (int c = 0; c < 512; c++) s += qrow[c] * kr[c];
    logit[t] = s;
  }
  __syncthreads();
  if (t == 0) {
    for (int tt = 0; tt < 4; tt++) {
      float best = -1e30f; int bi = 0;
      for (int q = 0; q < P2C; q++) if (logit[q] > best) { best = logit[q]; bi = q; }
      ridx[np * 4 + tt] = bi;
      logit[bi] = -1e30f;
    }
  }
}

// ---- LePE depthwise 3x3 (zero pad), transposed weights lwt[9][512] (coalesced) ----
__global__ __launch_bounds__(256) void k_lepe(const u16* __restrict__ qkvh,
                                              const float* __restrict__ lwt, const float* __restrict__ lb,
                                              u16* __restrict__ lepe) {
  int t = blockIdx.x * 256 + threadIdx.x;
  int r = t >> 6, c8 = (t & 63) << 3;
  int n = r / (P2C * 64); int rem = r - n * (P2C * 64);
  int p = rem >> 6, pix = rem & 63;
  int y = (p / 7) * 8 + (pix >> 3), xx = (p % 7) * 8 + (pix & 7);
  float acc[8];
  {
    float4 b0 = *(const float4*)(lb + c8), b1 = *(const float4*)(lb + c8 + 4);
    acc[0]=b0.x; acc[1]=b0.y; acc[2]=b0.z; acc[3]=b0.w;
    acc[4]=b1.x; acc[5]=b1.y; acc[6]=b1.z; acc[7]=b1.w;
  }
#pragma unroll
  for (int dy = -1; dy <= 1; dy++) {
#pragma unroll
    for (int dx = -1; dx <= 1; dx++) {
      int yy = y + dy, xz = xx + dx;
      if (yy < 0 || yy >= HH || xz < 0 || xz >= WWI) continue;
      int tap = (dy + 1) * 3 + (dx + 1);
      int p2 = (yy >> 3) * 7 + (xz >> 3), px2 = (yy & 7) * 8 + (xz & 7);
      const u16* v = qkvh + ((size_t)((n * P2C + p2) * 64 + px2)) * CQKV + 1024 + c8;
      u16x8 a = *(const u16x8*)v;
      const float* wrow = lwt + tap * 512 + c8;
      float4 w0 = *(const float4*)wrow, w1 = *(const float4*)(wrow + 4);
      float ww[8] = {w0.x, w0.y, w0.z, w0.w, w1.x, w1.y, w1.z, w1.w};
#pragma unroll
      for (int i = 0; i < 8; i++) acc[i] += bf2f(a[i]) * ww[i];
    }
  }
  u16x8 o;
#pragma unroll
  for (int i = 0; i < 8; i++) o[i] = f2bf(acc[i]);
  *(u16x8*)(lepe + (size_t)r * CDIM + c8) = o;
}

// ---- attention: block=(np, head-quad), wave=head. Swapped S^T=K*Q^T.
//      BOTH K and V staged in LDS (64KB each, 128KB total, 1 block/CU):
//      K: 256 rows x 256B (quad's 128 ch) from qkvh, 16B-chunk XOR swz cd^(row&15);
//      V: 512 strips of 128B from vT, chunk swz c^(colL&7). All staging coalesced
//      global_load_lds, LDS dest linear, swizzle applied on global src + LDS read.
//      softmax exp2(fma); P->bf16 cvt_pk. Epilogue: + lepe, A2 [hi|lo]. ----
__global__ __launch_bounds__(256) void k_attn(const u16* __restrict__ qkvh,
                                              const u16* __restrict__ vT,
                                              const int* __restrict__ ridx,
                                              const u16* __restrict__ lepe, u16* __restrict__ A2) {
  __shared__ u16 Ks[32768];    // 64 KB
  __shared__ u16 Vs[32768];    // 64 KB
  int b = blockIdx.x;
  int mq = b & 3, np = b >> 2;
  int n = np / P2C;
  int tid = threadIdx.x;
  int wid = tid >> 6, lane = tid & 63;
  int m = (mq << 2) + wid;
  int l15 = lane & 15, h4 = lane >> 4;
  int krow[4];
#pragma unroll
  for (int w = 0; w < 4; w++) krow[w] = (n * P2C + ridx[np * 4 + w]) * 64;
  size_t qrow0 = (size_t)np * 64;
  union FR  { s16x8 s; u16 u[8]; };
  union FRu { s16x8 s; unsigned w[4]; };
  f32x4 zero = {0.f, 0.f, 0.f, 0.f};
  int colbase = mq << 7;
  // ---- stage K: row = win*64+key (256 rows x 16 chunks of 16B = quad's 128 ch)
  //      dest chunk cd holds source chunk cd ^ (row&15)
#pragma unroll
  for (int i = 0; i < 16; i++) {
    int ch = i * 256 + tid;
    int row = ch >> 4, cd = ch & 15;
    int cs = cd ^ (row & 15);
    gld16(qkvh + (size_t)(krow[row >> 6] + (row & 63)) * CQKV + 512 + colbase + cs * 8,
          (char*)Ks + ch * 16);
  }
  // ---- stage V: strip = colL*4 + w (128B each), dest chunk c16d = src c16d ^ (colL&7)
#pragma unroll
  for (int i = 0; i < 16; i++) {
    int ch = i * 256 + tid;
    int strip = ch >> 3, c16d = ch & 7;
    int colL = strip >> 2, w = strip & 3;
    int c16s = c16d ^ (colL & 7);
    gld16(vT + (size_t)(colbase + colL) * NROWS + krow[w] + c16s * 8, (char*)Vs + ch * 16);
  }
  __syncthreads();
  // hoisted K fragments from LDS (fq-independent): row = fk*16+l15, chunk (wid*4+h4)^l15
  FR kf[16];
#pragma unroll
  for (int fk = 0; fk < 16; fk++) {
    int row = fk * 16 + l15;
    kf[fk].s = *(const s16x8*)((const char*)Ks + row * 256 + ((((wid << 2) + h4) ^ l15) << 4));
  }
#pragma unroll
  for (int fq = 0; fq < 4; fq++) {
    s16x8 qf = *(const s16x8*)(qkvh + (qrow0 + fq * 16 + l15) * CQKV + m * 32 + h4 * 8);
    f32x4 st[16];
#pragma unroll
    for (int fk = 0; fk < 16; fk++)
      st[fk] = __builtin_amdgcn_mfma_f32_16x16x32_bf16(kf[fk].s, qf, zero, 0, 0, 0);
    float mx = -1e30f;
#pragma unroll
    for (int fk = 0; fk < 16; fk++)
#pragma unroll
      for (int rg = 0; rg < 4; rg++) mx = fmaxf(mx, st[fk][rg]);
    mx = fmaxf(mx, __shfl_xor(mx, 16));
    mx = fmaxf(mx, __shfl_xor(mx, 32));
    float nmc = -mx * SC_LOG2E;
    float sum = 0.f;
#pragma unroll
    for (int fk = 0; fk < 16; fk++)
#pragma unroll
      for (int rg = 0; rg < 4; rg++) {
        float e = exp2f(fmaf(st[fk][rg], SC_LOG2E, nmc));
        st[fk][rg] = e; sum += e;
      }
    sum += __shfl_xor(sum, 16);
    sum += __shfl_xor(sum, 32);
    f32x4 oacc[2] = {zero, zero};
#pragma unroll
    for (int s8 = 0; s8 < 8; s8++) {
      FRu pa;
      pa.w[0] = cvtpk(st[2 * s8][0],     st[2 * s8][1]);
      pa.w[1] = cvtpk(st[2 * s8][2],     st[2 * s8][3]);
      pa.w[2] = cvtpk(st[2 * s8 + 1][0], st[2 * s8 + 1][1]);
      pa.w[3] = cvtpk(st[2 * s8 + 1][2], st[2 * s8 + 1][3]);
      int wv = s8 >> 1;
      int c16 = ((s8 & 1) << 2) + (h4 >> 1);
      int lo8 = (h4 & 1) << 3;
#pragma unroll
      for (int fd = 0; fd < 2; fd++) {
        int colL = (wid << 5) + (fd << 4) + l15;
        int strip = (colL << 2) + wv;
        int swz = colL & 7;
        const char* base = (const char*)Vs + strip * 128 + lo8;
        FR vf;
        *(u16x4*)&vf.u[0] = *(const u16x4*)(base + ((c16 ^ swz) << 4));
        *(u16x4*)&vf.u[4] = *(const u16x4*)(base + (((c16 + 2) ^ swz) << 4));
        oacc[fd] = __builtin_amdgcn_mfma_f32_16x16x32_bf16(pa.s, vf.s, oacc[fd], 0, 0, 0);
      }
    }
#pragma unroll
    for (int rg = 0; rg < 4; rg++) {
      float sq = __shfl(sum, (h4 << 2) + rg);
      int q = fq * 16 + (h4 << 2) + rg;
#pragma unroll
      for (int fd = 0; fd < 2; fd++) {
        int col = m * 32 + fd * 16 + l15;
        size_t row = qrow0 + q;
        float val = oacc[fd][rg] / sq + bf2f(lepe[row * CDIM + col]);
        u16 hi = f2bf(val);
        u16 lo = f2bf(val - bf2f(hi));
        A2[row * 1024 + col]       = hi;
        A2[row * 1024 + 512 + col] = lo;
      }
    }
  }
}

extern "C" void kernel_launch(void* const* d_in, const int* in_sizes, int n_in,
                              void* d_out, int out_size, void* d_ws, size_t ws_size,
                              hipStream_t stream) {
  (void)in_sizes; (void)n_in; (void)out_size; (void)ws_size;
  const float* x      = (const float*)d_in[0];
  const float* qkv_w  = (const float*)d_in[1];
  const float* qkv_b  = (const float*)d_in[2];
  const float* wo_w   = (const float*)d_in[3];
  const float* wo_b   = (const float*)d_in[4];
  const float* lepe_w = (const float*)d_in[5];
  const float* lepe_b = (const float*)d_in[6];
  float* out = (float*)d_out;
  char* ws = (char*)d_ws;
  size_t off = 0;
  auto alc = [&](size_t b) { char* p = ws + off; off += (b + 255) & ~(size_t)255; return p; };
  u16*   B1    = (u16*)  alc((size_t)1024 * CQKV * 2);        //  3.1 MB  (q,k rows, 3-term)
  u16*   Bv    = (u16*)  alc((size_t)512 * 1024 * 2);         //  1.0 MB  (v rows, 2-term)
  u16*   B2    = (u16*)  alc((size_t)CDIM * CQKV * 2);        //  1.6 MB
  float* lwt   = (float*)alc((size_t)9 * 512 * 4);            //  18 KB
  u16*   qkvh  = (u16*)  alc((size_t)NROWS * CQKV * 2);       // 77.1 MB
  u16*   vT    = (u16*)  alc((size_t)CDIM * NROWS * 2);       // 25.7 MB (v transposed)
  float* qw    = (float*)alc((size_t)NB * P2C * CDIM * 4);    //  0.8 MB
  float* kw    = (float*)alc((size_t)NB * P2C * CDIM * 4);    //  0.8 MB
  int*   ridx  = (int*)  alc((size_t)NB * P2C * 4 * 4);       //  6 KB
  u16*   lepe  = (u16*)  alc((size_t)NROWS * CDIM * 2);       // 25.7 MB
  u16*   A12   = (u16*)  alc((size_t)NROWS * 1024 * 2);       // 51.4 MB (A1, later A2)
  // total ~187 MB

  k_prep_a1<<<dim3(6272), dim3(256), 0, stream>>>(x, A12);
  k_prep_b <<<dim3(256),  dim3(256), 0, stream>>>(qkv_w, B1);     // rows 0..1023 (q,k)
  k_prep_bv<<<dim3(128),  dim3(256), 0, stream>>>(qkv_w, Bv);     // rows 1024..1535 (v)
  k_prep_b <<<dim3(128),  dim3(256), 0, stream>>>(wo_w, B2);
  k_prep_lw<<<dim3(18),   dim3(256), 0, stream>>>(lepe_w, lwt);
  k_gemm_h <<<dim3(1568), dim3(256), 0, stream>>>(A12, B1, CQKV, CQKV, 8,
                                                  qkv_b, qkvh, 0, qw, kw, nullptr);
  k_gemm_h <<<dim3(784),  dim3(256), 0, stream>>>(A12, Bv, 1024, 1024, 4,
                                                  qkv_b + 1024, qkvh, 1024, nullptr, nullptr, vT);
  k_route <<<dim3(392),  dim3(64),  0, stream>>>(qw, kw, ridx);
  k_lepe  <<<dim3(6272), dim3(256), 0, stream>>>(qkvh, lwt, lepe_b, lepe);
  k_attn  <<<dim3(1568), dim3(256), 0, stream>>>(qkvh, vT, ridx, lepe, A12);
  k_gemm_out<<<dim3(784), dim3(256), 0, stream>>>(A12, B2, out, wo_b);
}